// Round 1
// baseline (1397.662 us; speedup 1.0000x reference)
//
#include <hip/hip_runtime.h>
#include <hip/hip_bf16.h>

constexpr int kNN  = 10000;   // nodes
constexpr int kTT  = 12;      // timesteps
constexpr int kFIN = 32;      // input features
constexpr int kHH  = 64;      // hidden
constexpr int kH4  = 256;     // 4*hidden (gates)
constexpr int kOUT = 16;      // output features
constexpr int kNE  = 160000;  // edges

__device__ __forceinline__ float sigf(float x){ return 1.f/(1.f+__expf(-x)); }
__device__ __forceinline__ float tanh_fast(float x){
  float xc = fminf(fmaxf(x,-30.f),30.f);
  float e = __expf(-2.f*xc);
  return (1.f-e)/(1.f+e);
}
__device__ __forceinline__ float rdlane(float v, int l){
  return __int_as_float(__builtin_amdgcn_readlane(__float_as_int(v), l));
}

// Detect whether edge_index arrived as int64 (JAX x64) or int32 (default
// canonicalization). Under int32 the odd words are random node ids (OR != 0);
// under little-endian int64 every odd word is a zero hi-word.
__global__ void k_detect(const int* __restrict__ ei, int* __restrict__ is64){
  __shared__ int any;
  if (threadIdx.x==0) any = 0;
  __syncthreads();
  int a = 0;
  for (int i = threadIdx.x; i < kNE; i += 256) a |= ei[2*i+1];
  if (a) atomicOr(&any, 1);
  __syncthreads();
  if (threadIdx.x==0) is64[0] = any ? 0 : 1;
}

__global__ void k_deg(const int* __restrict__ ei, const int* __restrict__ is64,
                      int* __restrict__ cnt){
  int e = blockIdx.x*256 + threadIdx.x;
  if (e >= kNE) return;
  int c = is64[0] ? ei[2*(kNE+e)] : ei[kNE+e];
  atomicAdd(&cnt[c], 1);
}

// Exclusive scan of in-degree counts (single block) + dis = rsqrt(deg+selfloop)
__global__ void k_scan(const int* __restrict__ cnt, int* __restrict__ offs,
                       float* __restrict__ dis){
  __shared__ int part[256];
  int tid = threadIdx.x;
  const int CH = (kNN + 255)/256;
  int lo = tid*CH, hi = min(lo+CH, kNN);
  int s = 0;
  for (int i = lo; i < hi; ++i) s += cnt[i];
  part[tid] = s;
  __syncthreads();
  if (tid == 0){
    int run = 0;
    for (int i = 0; i < 256; ++i){ int v = part[i]; part[i] = run; run += v; }
  }
  __syncthreads();
  int run = part[tid];
  for (int i = lo; i < hi; ++i){ offs[i] = run; run += cnt[i]; }
  if (hi == kNN) offs[kNN] = run;
  for (int i = tid; i < kNN; i += 256) dis[i] = rsqrtf((float)(cnt[i]+1));
}

__global__ void k_scatter(const int* __restrict__ ei, const int* __restrict__ is64,
                          const int* __restrict__ offs, int* __restrict__ cur,
                          const float* __restrict__ dis,
                          int* __restrict__ esrc, float* __restrict__ ew){
  int e = blockIdx.x*256 + threadIdx.x;
  if (e >= kNE) return;
  int f = is64[0];
  int r = f ? ei[2*e]         : ei[e];
  int c = f ? ei[2*(kNE+e)]   : ei[kNE+e];
  int p = offs[c] + atomicAdd(&cur[c], 1);
  esrc[p] = r;
  ew[p] = dis[r]*dis[c];
}

// Tiled fp32 GEMM: out[M,N] = in[M,K] @ W[K,N] (+ b0 + b1).
// XT: input row m=(n*TT+t) is read from x at ((t*NN+n)*K) — fused transpose.
// WTR: W stored (N,K) row-major (e.g. wih) — transposed into LDS.
template<int K, int N, bool XT, bool WTR>
__global__ __launch_bounds__(256) void k_gemm(const float* __restrict__ in,
                      const float* __restrict__ Wg,
                      const float* __restrict__ b0, const float* __restrict__ b1,
                      float* __restrict__ out){
  constexpr int COLG = N/4;           // threads across columns (float4 each)
  constexpr int ROWG = 256/COLG;
  constexpr int MR   = (N==64)?4:8;   // rows per thread
  constexpr int MTILE= ROWG*MR;       // 64 (N=64) or 32 (N=256)
  constexpr int KC   = (N==256)?32:K; // K-chunk so Wl fits LDS
  constexpr int AP   = K + 4;         // padded A row
  __shared__ float Wl[KC*N];
  __shared__ float Al[MTILE*AP];
  int tid = threadIdx.x;
  int m0 = blockIdx.x*MTILE;
  for (int idx = tid; idx < MTILE*K; idx += 256){
    int r = idx/K, k = idx - r*K;
    int m = m0 + r;
    int off;
    if (XT){ int n = m/kTT, t = m - n*kTT; off = (t*kNN + n)*K + k; }
    else    off = m*K + k;
    Al[r*AP + k] = in[off];
  }
  int cg = tid % COLG, rg = tid / COLG;
  int c0 = cg*4, r0 = rg*MR;
  float acc[MR][4];
  #pragma unroll
  for (int r=0;r<MR;++r){acc[r][0]=0.f;acc[r][1]=0.f;acc[r][2]=0.f;acc[r][3]=0.f;}
  for (int kc = 0; kc < K; kc += KC){
    __syncthreads();
    for (int idx = tid; idx < KC*N; idx += 256){
      int k = idx/N, j = idx - k*N;
      Wl[idx] = WTR ? Wg[j*K + kc + k] : Wg[(kc+k)*N + j];
    }
    __syncthreads();
    #pragma unroll 4
    for (int k = 0; k < KC; ++k){
      float4 w = *(const float4*)&Wl[k*N + c0];
      #pragma unroll
      for (int r = 0; r < MR; ++r){
        float a = Al[(r0+r)*AP + kc + k];
        acc[r][0] = fmaf(a, w.x, acc[r][0]);
        acc[r][1] = fmaf(a, w.y, acc[r][1]);
        acc[r][2] = fmaf(a, w.z, acc[r][2]);
        acc[r][3] = fmaf(a, w.w, acc[r][3]);
      }
    }
  }
  float4 bb = make_float4(0.f,0.f,0.f,0.f);
  if (b0){ bb.x += b0[c0]; bb.y += b0[c0+1]; bb.z += b0[c0+2]; bb.w += b0[c0+3]; }
  if (b1){ bb.x += b1[c0]; bb.y += b1[c0+1]; bb.z += b1[c0+2]; bb.w += b1[c0+3]; }
  #pragma unroll
  for (int r = 0; r < MR; ++r){
    float4 v = make_float4(acc[r][0]+bb.x, acc[r][1]+bb.y,
                           acc[r][2]+bb.z, acc[r][3]+bb.w);
    *(float4*)&out[(m0 + r0 + r)*N + c0] = v;
  }
}

// GCN aggregation: one wave per (n,t), lane = feature. t-major grid so each
// 2.5MB t-slice stays L2-resident. out = relu(dis[n]^2*h[n] + sum w_e h[src] + b)
__global__ __launch_bounds__(256) void k_agg(const float* __restrict__ hin,
                     float* __restrict__ hout,
                     const float* __restrict__ bias, const float* __restrict__ dis,
                     const int* __restrict__ offs, const int* __restrict__ esrc,
                     const float* __restrict__ ew){
  int wid = threadIdx.x >> 6, lane = threadIdx.x & 63;
  int gw = blockIdx.x*4 + wid;          // gw = t*kNN + n  (t-major)
  int t = gw / kNN, n = gw - t*kNN;
  float d = dis[n];
  float acc = d*d*hin[(n*kTT + t)*kHH + lane];
  int e0 = offs[n], e1 = offs[n+1];
  for (int e = e0; e < e1; ++e){
    int s = esrc[e]; float w = ew[e];
    acc = fmaf(w, hin[(s*kTT + t)*kHH + lane], acc);
  }
  hout[(n*kTT + t)*kHH + lane] = fmaxf(acc + bias[lane], 0.f);
}

// LSTM recurrence, one layer. 4 nodes per wave, lane = hidden unit.
// Wp[j][4*l+q] = whh[q*64+l][j]  -> lane l reads one float4 (i,f,g,o weights)
// per j; h_j broadcast via v_readlane (no LDS for h). gx precomputed.
__global__ __launch_bounds__(256) void k_rec(const float* __restrict__ gx,
                     const float* __restrict__ whh, float* __restrict__ hout){
  __shared__ float Wp[kHH*kH4];   // 64KB
  int tid = threadIdx.x;
  for (int idx = tid; idx < kHH*kH4; idx += 256){
    int j = idx >> 8, r = idx & 255, l = r >> 2, q = r & 3;
    Wp[idx] = whh[(q*kHH + l)*kHH + j];
  }
  __syncthreads();
  int wid = tid >> 6, lane = tid & 63;
  int nb = blockIdx.x*16 + wid*4;
  float h[4] = {0.f,0.f,0.f,0.f}, c[4] = {0.f,0.f,0.f,0.f};
  for (int t = 0; t < kTT; ++t){
    float acc[4][4];
    #pragma unroll
    for (int m=0;m<4;++m){acc[m][0]=0.f;acc[m][1]=0.f;acc[m][2]=0.f;acc[m][3]=0.f;}
    #pragma unroll
    for (int j = 0; j < kHH; ++j){
      float4 w = *(const float4*)&Wp[(j << 8) + (lane << 2)];
      #pragma unroll
      for (int m = 0; m < 4; ++m){
        float hj = rdlane(h[m], j);
        acc[m][0] = fmaf(hj, w.x, acc[m][0]);
        acc[m][1] = fmaf(hj, w.y, acc[m][1]);
        acc[m][2] = fmaf(hj, w.z, acc[m][2]);
        acc[m][3] = fmaf(hj, w.w, acc[m][3]);
      }
    }
    #pragma unroll
    for (int m = 0; m < 4; ++m){
      const float* gp = gx + ((nb + m)*kTT + t)*kH4;
      float gi = acc[m][0] + gp[lane];
      float gf = acc[m][1] + gp[kHH + lane];
      float gg = acc[m][2] + gp[2*kHH + lane];
      float go = acc[m][3] + gp[3*kHH + lane];
      float ii = sigf(gi), ff = sigf(gf), gt = tanh_fast(gg), oo = sigf(go);
      c[m] = ff*c[m] + ii*gt;
      float hn = oo * tanh_fast(c[m]);
      h[m] = hn;
      hout[((nb + m)*kTT + t)*kHH + lane] = hn;
    }
  }
}

__global__ void k_fc(const float* __restrict__ h, const float* __restrict__ w,
                     const float* __restrict__ b, float* __restrict__ out){
  int tid = blockIdx.x*256 + threadIdx.x;
  if (tid >= kNN*kOUT) return;
  int n = tid / kOUT, o = tid - n*kOUT;
  const float* hp = h + (n*kTT + (kTT-1))*kHH;
  const float* wp = w + o*kHH;
  float acc = b[o];
  #pragma unroll 8
  for (int j = 0; j < kHH; ++j) acc = fmaf(hp[j], wp[j], acc);
  out[tid] = acc;
}

extern "C" void kernel_launch(void* const* d_in, const int* in_sizes, int n_in,
                              void* d_out, int out_size, void* d_ws, size_t ws_size,
                              hipStream_t stream){
  const float* x    = (const float*)d_in[0];
  const int*   ei   = (const int*)  d_in[1];
  const float* gw0  = (const float*)d_in[2];
  const float* gb0  = (const float*)d_in[3];
  const float* gw1  = (const float*)d_in[4];
  const float* gb1  = (const float*)d_in[5];
  const float* wih0 = (const float*)d_in[6];
  const float* whh0 = (const float*)d_in[7];
  const float* bih0 = (const float*)d_in[8];
  const float* bhh0 = (const float*)d_in[9];
  const float* wih1 = (const float*)d_in[10];
  const float* whh1 = (const float*)d_in[11];
  const float* bih1 = (const float*)d_in[12];
  const float* bhh1 = (const float*)d_in[13];
  const float* fcw  = (const float*)d_in[14];
  const float* fcb  = (const float*)d_in[15];
  float* out = (float*)d_out;

  char* ws = (char*)d_ws;
  size_t p = 0;
  auto carve = [&](size_t bytes)->char*{
    char* r = ws + p;
    p += (bytes + 255) & ~(size_t)255;
    return r;
  };
  int*   is64 = (int*)  carve(256);
  int*   cnt  = (int*)  carve(sizeof(int)*kNN);
  int*   cur  = (int*)  carve(sizeof(int)*kNN);
  int*   offs = (int*)  carve(sizeof(int)*(kNN+1));
  float* dis  = (float*)carve(sizeof(float)*kNN);
  int*   esrc = (int*)  carve(sizeof(int)*kNE);
  float* ew   = (float*)carve(sizeof(float)*kNE);
  float* bufA = (float*)carve(sizeof(float)*(size_t)kNN*kTT*kHH);   // 30.7MB
  float* bufB = (float*)carve(sizeof(float)*(size_t)kNN*kTT*kHH);   // 30.7MB
  float* bufC = (float*)carve(sizeof(float)*(size_t)kNN*kTT*kH4);   // 122.9MB
  (void)ws_size; (void)in_sizes; (void)n_in; (void)out_size;

  hipMemsetAsync(cnt, 0, sizeof(int)*kNN, stream);
  hipMemsetAsync(cur, 0, sizeof(int)*kNN, stream);
  k_detect <<<1, 256, 0, stream>>>(ei, is64);
  k_deg    <<<(kNE+255)/256, 256, 0, stream>>>(ei, is64, cnt);
  k_scan   <<<1, 256, 0, stream>>>(cnt, offs, dis);
  k_scatter<<<(kNE+255)/256, 256, 0, stream>>>(ei, is64, offs, cur, dis, esrc, ew);

  // GCN layer 0: x @ gw0 -> bufA ; aggregate+bias+relu -> bufB
  k_gemm<kFIN, kHH, true,  false><<<(kNN*kTT)/64, 256, 0, stream>>>(x,    gw0, nullptr, nullptr, bufA);
  k_agg <<<(kNN*kTT)/4, 256, 0, stream>>>(bufA, bufB, gb0, dis, offs, esrc, ew);
  // GCN layer 1
  k_gemm<kHH,  kHH, false, false><<<(kNN*kTT)/64, 256, 0, stream>>>(bufB, gw1, nullptr, nullptr, bufA);
  k_agg <<<(kNN*kTT)/4, 256, 0, stream>>>(bufA, bufB, gb1, dis, offs, esrc, ew);

  // LSTM layer 0: gx = h @ wih0^T + (bih0+bhh0) -> bufC ; recurrence -> bufA
  k_gemm<kHH, kH4, false, true><<<(kNN*kTT)/32, 256, 0, stream>>>(bufB, wih0, bih0, bhh0, bufC);
  k_rec <<<kNN/16, 256, 0, stream>>>(bufC, whh0, bufA);
  // LSTM layer 1
  k_gemm<kHH, kH4, false, true><<<(kNN*kTT)/32, 256, 0, stream>>>(bufA, wih1, bih1, bhh1, bufC);
  k_rec <<<kNN/16, 256, 0, stream>>>(bufC, whh1, bufB);

  // FC on last timestep
  k_fc<<<(kNN*kOUT+255)/256, 256, 0, stream>>>(bufB, fcw, fcb, out);
}

// Round 2
// 1007.646 us; speedup vs baseline: 1.3871x; 1.3871x over previous
//
#include <hip/hip_runtime.h>
#include <hip/hip_bf16.h>

constexpr int kNN  = 10000;   // nodes
constexpr int kTT  = 12;      // timesteps
constexpr int kFIN = 32;      // input features
constexpr int kHH  = 64;      // hidden
constexpr int kH4  = 256;     // 4*hidden (gates)
constexpr int kOUT = 16;      // output features
constexpr int kNE  = 160000;  // edges

typedef _Float16 half8 __attribute__((ext_vector_type(8)));

__device__ __forceinline__ float sigf(float x){ return 1.f/(1.f+__expf(-x)); }
__device__ __forceinline__ float tanh_fast(float x){
  float xc = fminf(fmaxf(x,-30.f),30.f);
  float e = __expf(-2.f*xc);
  return (1.f-e)/(1.f+e);
}
__device__ __forceinline__ float rdlane(float v, int l){
  return __int_as_float(__builtin_amdgcn_readlane(__float_as_int(v), l));
}

// Detect whether edge_index arrived as int64 (JAX x64) or int32 (default
// canonicalization). Under int32 the odd words are random node ids (OR != 0);
// under little-endian int64 every odd word is a zero hi-word.
__global__ void k_detect(const int* __restrict__ ei, int* __restrict__ is64){
  __shared__ int any;
  if (threadIdx.x==0) any = 0;
  __syncthreads();
  int a = 0;
  for (int i = threadIdx.x; i < kNE; i += 256) a |= ei[2*i+1];
  if (a) atomicOr(&any, 1);
  __syncthreads();
  if (threadIdx.x==0) is64[0] = any ? 0 : 1;
}

__global__ void k_deg(const int* __restrict__ ei, const int* __restrict__ is64,
                      int* __restrict__ cnt){
  int e = blockIdx.x*256 + threadIdx.x;
  if (e >= kNE) return;
  int c = is64[0] ? ei[2*(kNE+e)] : ei[kNE+e];
  atomicAdd(&cnt[c], 1);
}

// Exclusive scan of in-degree counts (single block) + dis = rsqrt(deg+selfloop)
__global__ void k_scan(const int* __restrict__ cnt, int* __restrict__ offs,
                       float* __restrict__ dis){
  __shared__ int part[256];
  int tid = threadIdx.x;
  const int CH = (kNN + 255)/256;
  int lo = tid*CH, hi = min(lo+CH, kNN);
  int s = 0;
  for (int i = lo; i < hi; ++i) s += cnt[i];
  part[tid] = s;
  __syncthreads();
  if (tid == 0){
    int run = 0;
    for (int i = 0; i < 256; ++i){ int v = part[i]; part[i] = run; run += v; }
  }
  __syncthreads();
  int run = part[tid];
  for (int i = lo; i < hi; ++i){ offs[i] = run; run += cnt[i]; }
  if (hi == kNN) offs[kNN] = run;
  for (int i = tid; i < kNN; i += 256) dis[i] = rsqrtf((float)(cnt[i]+1));
}

__global__ void k_scatter(const int* __restrict__ ei, const int* __restrict__ is64,
                          const int* __restrict__ offs, int* __restrict__ cur,
                          const float* __restrict__ dis,
                          int* __restrict__ esrc, float* __restrict__ ew){
  int e = blockIdx.x*256 + threadIdx.x;
  if (e >= kNE) return;
  int f = is64[0];
  int r = f ? ei[2*e]         : ei[e];
  int c = f ? ei[2*(kNE+e)]   : ei[kNE+e];
  int p = offs[c] + atomicAdd(&cur[c], 1);
  esrc[p] = r;
  ew[p] = dis[r]*dis[c];
}

// Tiled fp32 GEMM: out[M,N] = in[M,K] @ W[K,N] (+ b0 + b1).
// XT: input row m=(n*TT+t) is read from x at ((t*NN+n)*K) — fused transpose.
// WTR: W stored (N,K) row-major (e.g. wih) — transposed into LDS.
template<int K, int N, bool XT, bool WTR>
__global__ __launch_bounds__(256) void k_gemm(const float* __restrict__ in,
                      const float* __restrict__ Wg,
                      const float* __restrict__ b0, const float* __restrict__ b1,
                      float* __restrict__ out){
  constexpr int COLG = N/4;           // threads across columns (float4 each)
  constexpr int ROWG = 256/COLG;
  constexpr int MR   = (N==64)?4:8;   // rows per thread
  constexpr int MTILE= ROWG*MR;       // 64 (N=64) or 32 (N=256)
  constexpr int KC   = (N==256)?32:K; // K-chunk so Wl fits LDS
  constexpr int AP   = K + 4;         // padded A row (keeps 16B alignment: K%4==0)
  __shared__ float Wl[KC*N];
  __shared__ float Al[MTILE*AP];
  int tid = threadIdx.x;
  int m0 = blockIdx.x*MTILE;
  for (int idx = tid; idx < MTILE*K; idx += 256){
    int r = idx/K, k = idx - r*K;
    int m = m0 + r;
    int off;
    if (XT){ int n = m/kTT, t = m - n*kTT; off = (t*kNN + n)*K + k; }
    else    off = m*K + k;
    Al[r*AP + k] = in[off];
  }
  int cg = tid % COLG, rg = tid / COLG;
  int c0 = cg*4, r0 = rg*MR;
  float acc[MR][4];
  #pragma unroll
  for (int r=0;r<MR;++r){acc[r][0]=0.f;acc[r][1]=0.f;acc[r][2]=0.f;acc[r][3]=0.f;}
  for (int kc = 0; kc < K; kc += KC){
    __syncthreads();
    for (int idx = tid; idx < KC*N; idx += 256){
      int k = idx/N, j = idx - k*N;
      Wl[idx] = WTR ? Wg[j*K + kc + k] : Wg[(kc+k)*N + j];
    }
    __syncthreads();
    #pragma unroll 2
    for (int k = 0; k < KC; k += 4){
      float4 wv[4];
      #pragma unroll
      for (int kk = 0; kk < 4; ++kk) wv[kk] = *(const float4*)&Wl[(k+kk)*N + c0];
      #pragma unroll
      for (int r = 0; r < MR; ++r){
        float4 a4 = *(const float4*)&Al[(r0+r)*AP + kc + k];
        acc[r][0] = fmaf(a4.x, wv[0].x, acc[r][0]);
        acc[r][1] = fmaf(a4.x, wv[0].y, acc[r][1]);
        acc[r][2] = fmaf(a4.x, wv[0].z, acc[r][2]);
        acc[r][3] = fmaf(a4.x, wv[0].w, acc[r][3]);
        acc[r][0] = fmaf(a4.y, wv[1].x, acc[r][0]);
        acc[r][1] = fmaf(a4.y, wv[1].y, acc[r][1]);
        acc[r][2] = fmaf(a4.y, wv[1].z, acc[r][2]);
        acc[r][3] = fmaf(a4.y, wv[1].w, acc[r][3]);
        acc[r][0] = fmaf(a4.z, wv[2].x, acc[r][0]);
        acc[r][1] = fmaf(a4.z, wv[2].y, acc[r][1]);
        acc[r][2] = fmaf(a4.z, wv[2].z, acc[r][2]);
        acc[r][3] = fmaf(a4.z, wv[2].w, acc[r][3]);
        acc[r][0] = fmaf(a4.w, wv[3].x, acc[r][0]);
        acc[r][1] = fmaf(a4.w, wv[3].y, acc[r][1]);
        acc[r][2] = fmaf(a4.w, wv[3].z, acc[r][2]);
        acc[r][3] = fmaf(a4.w, wv[3].w, acc[r][3]);
      }
    }
  }
  float4 bb = make_float4(0.f,0.f,0.f,0.f);
  if (b0){ bb.x += b0[c0]; bb.y += b0[c0+1]; bb.z += b0[c0+2]; bb.w += b0[c0+3]; }
  if (b1){ bb.x += b1[c0]; bb.y += b1[c0+1]; bb.z += b1[c0+2]; bb.w += b1[c0+3]; }
  #pragma unroll
  for (int r = 0; r < MR; ++r){
    float4 v = make_float4(acc[r][0]+bb.x, acc[r][1]+bb.y,
                           acc[r][2]+bb.z, acc[r][3]+bb.w);
    *(float4*)&out[(m0 + r0 + r)*N + c0] = v;
  }
}

// GCN aggregation: one wave per NODE, all 12 timesteps at once (they share the
// edge list; the 12*64=768 floats of a node are contiguous). Each edge is
// 3 float4-coalesced 1KB wave loads. out = relu(d^2*h[n] + sum w_e h[src] + b)
__global__ __launch_bounds__(256) void k_agg(const float* __restrict__ hin,
                     float* __restrict__ hout,
                     const float* __restrict__ bias, const float* __restrict__ dis,
                     const int* __restrict__ offs, const int* __restrict__ esrc,
                     const float* __restrict__ ew){
  int wid = threadIdx.x >> 6, lane = threadIdx.x & 63;
  int n = blockIdx.x*4 + wid;
  if (n >= kNN) return;
  float d = dis[n];
  float ws = d*d;
  const float4* self = (const float4*)(hin + n*(kTT*kHH));
  float4 s0 = self[lane], s1 = self[64+lane], s2 = self[128+lane];
  float acc[12] = {ws*s0.x, ws*s0.y, ws*s0.z, ws*s0.w,
                   ws*s1.x, ws*s1.y, ws*s1.z, ws*s1.w,
                   ws*s2.x, ws*s2.y, ws*s2.z, ws*s2.w};
  int e0 = offs[n], e1 = offs[n+1];
  for (int e = e0; e < e1; ++e){
    int s = esrc[e]; float w = ew[e];
    const float4* hp = (const float4*)(hin + s*(kTT*kHH));
    float4 b0 = hp[lane], b1 = hp[64+lane], b2 = hp[128+lane];
    acc[0] = fmaf(w, b0.x, acc[0]); acc[1] = fmaf(w, b0.y, acc[1]);
    acc[2] = fmaf(w, b0.z, acc[2]); acc[3] = fmaf(w, b0.w, acc[3]);
    acc[4] = fmaf(w, b1.x, acc[4]); acc[5] = fmaf(w, b1.y, acc[5]);
    acc[6] = fmaf(w, b1.z, acc[6]); acc[7] = fmaf(w, b1.w, acc[7]);
    acc[8] = fmaf(w, b2.x, acc[8]); acc[9] = fmaf(w, b2.y, acc[9]);
    acc[10] = fmaf(w, b2.z, acc[10]); acc[11] = fmaf(w, b2.w, acc[11]);
  }
  // feature index of element (c*256 + lane*4 + r) is ((lane&15)*4 + r)
  float4 bb = *(const float4*)&bias[(lane & 15)*4];
  float4* op = (float4*)(hout + n*(kTT*kHH));
  op[lane]     = make_float4(fmaxf(acc[0]+bb.x,0.f), fmaxf(acc[1]+bb.y,0.f),
                             fmaxf(acc[2]+bb.z,0.f), fmaxf(acc[3]+bb.w,0.f));
  op[64+lane]  = make_float4(fmaxf(acc[4]+bb.x,0.f), fmaxf(acc[5]+bb.y,0.f),
                             fmaxf(acc[6]+bb.z,0.f), fmaxf(acc[7]+bb.w,0.f));
  op[128+lane] = make_float4(fmaxf(acc[8]+bb.x,0.f), fmaxf(acc[9]+bb.y,0.f),
                             fmaxf(acc[10]+bb.z,0.f), fmaxf(acc[11]+bb.w,0.f));
}

// LSTM recurrence. 8 nodes/wave, lane = hidden unit. Whh repacked fp16 in LDS:
// Wp[jp*512 + l*8 + s*4 + q] = whh[q*64+l][2*jp+s]  -> one ds_read_b128 per
// lane per j-pair feeds 64 FMAs (8 nodes x 4 gates x 2 j). h broadcast via
// v_readlane. gx gate dwords prefetched before the j-loop so global latency
// hides under ~6k cycles of FMA. LAST: only t=11 written (compact [n][64]).
template<bool LAST>
__global__ __launch_bounds__(256, 4) void k_rec(const float* __restrict__ gx,
                     const float* __restrict__ whh, float* __restrict__ hout){
  __shared__ alignas(16) _Float16 Wp[kHH*kH4];   // 32KB
  int tid = threadIdx.x;
  for (int idx = tid; idx < kHH*kH4; idx += 256){
    int jp = idx >> 9, r = idx & 511, l = r >> 3, s = (r >> 2) & 1, q = r & 3;
    int j = 2*jp + s;
    Wp[idx] = (_Float16)whh[(q*kHH + l)*kHH + j];
  }
  __syncthreads();
  int wid = tid >> 6, lane = tid & 63;
  int nb = blockIdx.x*32 + wid*8;
  float h[8], c[8];
  #pragma unroll
  for (int m = 0; m < 8; ++m){ h[m] = 0.f; c[m] = 0.f; }
  for (int t = 0; t < kTT; ++t){
    float g[8][4];
    #pragma unroll
    for (int m = 0; m < 8; ++m){
      int nm = min(nb + m, kNN-1);
      const float* gp = gx + (size_t)(nm*kTT + t)*kH4;
      g[m][0] = gp[lane];
      g[m][1] = gp[kHH + lane];
      g[m][2] = gp[2*kHH + lane];
      g[m][3] = gp[3*kHH + lane];
    }
    float acc[8][4];
    #pragma unroll
    for (int m = 0; m < 8; ++m){acc[m][0]=0.f;acc[m][1]=0.f;acc[m][2]=0.f;acc[m][3]=0.f;}
    #pragma unroll 8
    for (int jp = 0; jp < 32; ++jp){
      half8 wv = *(const half8*)&Wp[(jp << 9) + (lane << 3)];
      float wi0 = (float)wv[0], wf0 = (float)wv[1], wg0 = (float)wv[2], wo0 = (float)wv[3];
      float wi1 = (float)wv[4], wf1 = (float)wv[5], wg1 = (float)wv[6], wo1 = (float)wv[7];
      #pragma unroll
      for (int m = 0; m < 8; ++m){
        float h0 = rdlane(h[m], 2*jp);
        float h1 = rdlane(h[m], 2*jp + 1);
        acc[m][0] = fmaf(h0, wi0, acc[m][0]);
        acc[m][1] = fmaf(h0, wf0, acc[m][1]);
        acc[m][2] = fmaf(h0, wg0, acc[m][2]);
        acc[m][3] = fmaf(h0, wo0, acc[m][3]);
        acc[m][0] = fmaf(h1, wi1, acc[m][0]);
        acc[m][1] = fmaf(h1, wf1, acc[m][1]);
        acc[m][2] = fmaf(h1, wg1, acc[m][2]);
        acc[m][3] = fmaf(h1, wo1, acc[m][3]);
      }
    }
    #pragma unroll
    for (int m = 0; m < 8; ++m){
      float gi = acc[m][0] + g[m][0];
      float gf = acc[m][1] + g[m][1];
      float gg = acc[m][2] + g[m][2];
      float go = acc[m][3] + g[m][3];
      float ii = sigf(gi), ff = sigf(gf), gt = tanh_fast(gg), oo = sigf(go);
      c[m] = ff*c[m] + ii*gt;
      float hn = oo * tanh_fast(c[m]);
      h[m] = hn;
      if (!LAST){
        if (nb + m < kNN) hout[(size_t)((nb+m)*kTT + t)*kHH + lane] = hn;
      } else if (t == kTT-1){
        if (nb + m < kNN) hout[(size_t)(nb+m)*kHH + lane] = hn;
      }
    }
  }
}

// FC on compact last-timestep h: h is [kNN][64]
__global__ void k_fc(const float* __restrict__ h, const float* __restrict__ w,
                     const float* __restrict__ b, float* __restrict__ out){
  int tid = blockIdx.x*256 + threadIdx.x;
  if (tid >= kNN*kOUT) return;
  int n = tid / kOUT, o = tid - n*kOUT;
  const float* hp = h + (size_t)n*kHH;
  const float* wp = w + o*kHH;
  float acc = b[o];
  #pragma unroll 8
  for (int j = 0; j < kHH; ++j) acc = fmaf(hp[j], wp[j], acc);
  out[tid] = acc;
}

extern "C" void kernel_launch(void* const* d_in, const int* in_sizes, int n_in,
                              void* d_out, int out_size, void* d_ws, size_t ws_size,
                              hipStream_t stream){
  const float* x    = (const float*)d_in[0];
  const int*   ei   = (const int*)  d_in[1];
  const float* gw0  = (const float*)d_in[2];
  const float* gb0  = (const float*)d_in[3];
  const float* gw1  = (const float*)d_in[4];
  const float* gb1  = (const float*)d_in[5];
  const float* wih0 = (const float*)d_in[6];
  const float* whh0 = (const float*)d_in[7];
  const float* bih0 = (const float*)d_in[8];
  const float* bhh0 = (const float*)d_in[9];
  const float* wih1 = (const float*)d_in[10];
  const float* whh1 = (const float*)d_in[11];
  const float* bih1 = (const float*)d_in[12];
  const float* bhh1 = (const float*)d_in[13];
  const float* fcw  = (const float*)d_in[14];
  const float* fcb  = (const float*)d_in[15];
  float* out = (float*)d_out;

  char* ws = (char*)d_ws;
  size_t p = 0;
  auto carve = [&](size_t bytes)->char*{
    char* r = ws + p;
    p += (bytes + 255) & ~(size_t)255;
    return r;
  };
  int*   is64 = (int*)  carve(256);
  int*   cnt  = (int*)  carve(sizeof(int)*kNN);
  int*   cur  = (int*)  carve(sizeof(int)*kNN);
  int*   offs = (int*)  carve(sizeof(int)*(kNN+1));
  float* dis  = (float*)carve(sizeof(float)*kNN);
  int*   esrc = (int*)  carve(sizeof(int)*kNE);
  float* ew   = (float*)carve(sizeof(float)*kNE);
  float* bufA = (float*)carve(sizeof(float)*(size_t)kNN*kTT*kHH);   // 30.7MB
  float* bufB = (float*)carve(sizeof(float)*(size_t)kNN*kTT*kHH);   // 30.7MB
  float* bufC = (float*)carve(sizeof(float)*(size_t)kNN*kTT*kH4);   // 122.9MB
  (void)ws_size; (void)in_sizes; (void)n_in; (void)out_size;

  hipMemsetAsync(cnt, 0, sizeof(int)*kNN, stream);
  hipMemsetAsync(cur, 0, sizeof(int)*kNN, stream);
  k_detect <<<1, 256, 0, stream>>>(ei, is64);
  k_deg    <<<(kNE+255)/256, 256, 0, stream>>>(ei, is64, cnt);
  k_scan   <<<1, 256, 0, stream>>>(cnt, offs, dis);
  k_scatter<<<(kNE+255)/256, 256, 0, stream>>>(ei, is64, offs, cur, dis, esrc, ew);

  // GCN layer 0: x @ gw0 -> bufA ; aggregate+bias+relu -> bufB
  k_gemm<kFIN, kHH, true,  false><<<(kNN*kTT)/64, 256, 0, stream>>>(x,    gw0, nullptr, nullptr, bufA);
  k_agg <<<(kNN+3)/4, 256, 0, stream>>>(bufA, bufB, gb0, dis, offs, esrc, ew);
  // GCN layer 1
  k_gemm<kHH,  kHH, false, false><<<(kNN*kTT)/64, 256, 0, stream>>>(bufB, gw1, nullptr, nullptr, bufA);
  k_agg <<<(kNN+3)/4, 256, 0, stream>>>(bufA, bufB, gb1, dis, offs, esrc, ew);

  // LSTM layer 0: gx = h @ wih0^T + (bih0+bhh0) -> bufC ; recurrence -> bufA
  k_gemm<kHH, kH4, false, true><<<(kNN*kTT)/32, 256, 0, stream>>>(bufB, wih0, bih0, bhh0, bufC);
  k_rec<false><<<(kNN+31)/32, 256, 0, stream>>>(bufC, whh0, bufA);
  // LSTM layer 1 (recurrence keeps only t=11, compact [n][64])
  k_gemm<kHH, kH4, false, true><<<(kNN*kTT)/32, 256, 0, stream>>>(bufA, wih1, bih1, bhh1, bufC);
  k_rec<true><<<(kNN+31)/32, 256, 0, stream>>>(bufC, whh1, bufB);

  // FC on last timestep
  k_fc<<<(kNN*kOUT+255)/256, 256, 0, stream>>>(bufB, fcw, fcb, out);
}

// Round 3
// 674.690 us; speedup vs baseline: 2.0716x; 1.4935x over previous
//
#include <hip/hip_runtime.h>
#include <hip/hip_bf16.h>

constexpr int kNN  = 10000;   // nodes
constexpr int kTT  = 12;      // timesteps
constexpr int kFIN = 32;      // input features
constexpr int kHH  = 64;      // hidden
constexpr int kH4  = 256;     // 4*hidden (gates)
constexpr int kOUT = 16;      // output features
constexpr int kNE  = 160000;  // edges

typedef _Float16 half8 __attribute__((ext_vector_type(8)));
typedef float floatx4 __attribute__((ext_vector_type(4)));

__device__ __forceinline__ float sigf(float x){ return 1.f/(1.f+__expf(-x)); }
__device__ __forceinline__ float tanh_fast(float x){
  float xc = fminf(fmaxf(x,-30.f),30.f);
  float e = __expf(-2.f*xc);
  return (1.f-e)/(1.f+e);
}

// Detect whether edge_index arrived as int64 (JAX x64) or int32 (default
// canonicalization). Under int32 the odd words are random node ids (OR != 0);
// under little-endian int64 every odd word is a zero hi-word.
__global__ void k_detect(const int* __restrict__ ei, int* __restrict__ is64){
  __shared__ int any;
  if (threadIdx.x==0) any = 0;
  __syncthreads();
  int a = 0;
  for (int i = threadIdx.x; i < kNE; i += 256) a |= ei[2*i+1];
  if (a) atomicOr(&any, 1);
  __syncthreads();
  if (threadIdx.x==0) is64[0] = any ? 0 : 1;
}

__global__ void k_deg(const int* __restrict__ ei, const int* __restrict__ is64,
                      int* __restrict__ cnt){
  int e = blockIdx.x*256 + threadIdx.x;
  if (e >= kNE) return;
  int c = is64[0] ? ei[2*(kNE+e)] : ei[kNE+e];
  atomicAdd(&cnt[c], 1);
}

// Exclusive scan of in-degree counts (single block) + dis = rsqrt(deg+selfloop)
__global__ void k_scan(const int* __restrict__ cnt, int* __restrict__ offs,
                       float* __restrict__ dis){
  __shared__ int part[256];
  int tid = threadIdx.x;
  const int CH = (kNN + 255)/256;
  int lo = tid*CH, hi = min(lo+CH, kNN);
  int s = 0;
  for (int i = lo; i < hi; ++i) s += cnt[i];
  part[tid] = s;
  __syncthreads();
  if (tid == 0){
    int run = 0;
    for (int i = 0; i < 256; ++i){ int v = part[i]; part[i] = run; run += v; }
  }
  __syncthreads();
  int run = part[tid];
  for (int i = lo; i < hi; ++i){ offs[i] = run; run += cnt[i]; }
  if (hi == kNN) offs[kNN] = run;
  for (int i = tid; i < kNN; i += 256) dis[i] = rsqrtf((float)(cnt[i]+1));
}

__global__ void k_scatter(const int* __restrict__ ei, const int* __restrict__ is64,
                          const int* __restrict__ offs, int* __restrict__ cur,
                          const float* __restrict__ dis,
                          int* __restrict__ esrc, float* __restrict__ ew){
  int e = blockIdx.x*256 + threadIdx.x;
  if (e >= kNE) return;
  int f = is64[0];
  int r = f ? ei[2*e]         : ei[e];
  int c = f ? ei[2*(kNE+e)]   : ei[kNE+e];
  int p = offs[c] + atomicAdd(&cur[c], 1);
  esrc[p] = r;
  ew[p] = dis[r]*dis[c];
}

// Tiled fp32 GEMM: out[M,N] = in[M,K] @ W[K,N]. Rows m are t-major
// (m = t*kNN + n) for both in and out — x is natively t-major.
template<int K, int N>
__global__ __launch_bounds__(256) void k_gemm(const float* __restrict__ in,
                      const float* __restrict__ Wg,
                      float* __restrict__ out){
  constexpr int COLG = N/4;           // threads across columns (float4 each)
  constexpr int ROWG = 256/COLG;
  constexpr int MR   = 4;             // rows per thread
  constexpr int MTILE= ROWG*MR;       // 64
  constexpr int AP   = K + 4;         // padded A row (16B-aligned: K%4==0)
  __shared__ float Wl[K*N];
  __shared__ float Al[MTILE*AP];
  int tid = threadIdx.x;
  int m0 = blockIdx.x*MTILE;
  for (int idx = tid; idx < MTILE*K; idx += 256){
    int r = idx/K, k = idx - r*K;
    Al[r*AP + k] = in[(size_t)(m0 + r)*K + k];
  }
  for (int idx = tid; idx < K*N; idx += 256) Wl[idx] = Wg[idx];
  __syncthreads();
  int cg = tid % COLG, rg = tid / COLG;
  int c0 = cg*4, r0 = rg*MR;
  float acc[MR][4];
  #pragma unroll
  for (int r=0;r<MR;++r){acc[r][0]=0.f;acc[r][1]=0.f;acc[r][2]=0.f;acc[r][3]=0.f;}
  #pragma unroll 2
  for (int k = 0; k < K; k += 4){
    float4 wv[4];
    #pragma unroll
    for (int kk = 0; kk < 4; ++kk) wv[kk] = *(const float4*)&Wl[(k+kk)*N + c0];
    #pragma unroll
    for (int r = 0; r < MR; ++r){
      float4 a4 = *(const float4*)&Al[(r0+r)*AP + k];
      acc[r][0] = fmaf(a4.x, wv[0].x, acc[r][0]);
      acc[r][1] = fmaf(a4.x, wv[0].y, acc[r][1]);
      acc[r][2] = fmaf(a4.x, wv[0].z, acc[r][2]);
      acc[r][3] = fmaf(a4.x, wv[0].w, acc[r][3]);
      acc[r][0] = fmaf(a4.y, wv[1].x, acc[r][0]);
      acc[r][1] = fmaf(a4.y, wv[1].y, acc[r][1]);
      acc[r][2] = fmaf(a4.y, wv[1].z, acc[r][2]);
      acc[r][3] = fmaf(a4.y, wv[1].w, acc[r][3]);
      acc[r][0] = fmaf(a4.z, wv[2].x, acc[r][0]);
      acc[r][1] = fmaf(a4.z, wv[2].y, acc[r][1]);
      acc[r][2] = fmaf(a4.z, wv[2].z, acc[r][2]);
      acc[r][3] = fmaf(a4.z, wv[2].w, acc[r][3]);
      acc[r][0] = fmaf(a4.w, wv[3].x, acc[r][0]);
      acc[r][1] = fmaf(a4.w, wv[3].y, acc[r][1]);
      acc[r][2] = fmaf(a4.w, wv[3].z, acc[r][2]);
      acc[r][3] = fmaf(a4.w, wv[3].w, acc[r][3]);
    }
  }
  #pragma unroll
  for (int r = 0; r < MR; ++r){
    float4 v = make_float4(acc[r][0], acc[r][1], acc[r][2], acc[r][3]);
    *(float4*)&out[(size_t)(m0 + r0 + r)*N + c0] = v;
  }
}

// GCN aggregation, t-sliced: wave per (n,t), t-major grid so each 2.5MB
// t-slab stays L2-resident per XCD. lane = feature. Gathers are 256B/wave
// coalesced. out = relu(d^2*h[n] + sum w_e h[src] + b).
// TM: output t-major (feeds next gemm) else node-major (feeds LSTM).
template<bool TM>
__global__ __launch_bounds__(256) void k_agg(const float* __restrict__ hin,
                     float* __restrict__ hout,
                     const float* __restrict__ bias, const float* __restrict__ dis,
                     const int* __restrict__ offs, const int* __restrict__ esrc,
                     const float* __restrict__ ew){
  int wid = threadIdx.x >> 6, lane = threadIdx.x & 63;
  int gw = blockIdx.x*4 + wid;          // t-major: gw = t*kNN + n
  int t = gw / kNN, n = gw - t*kNN;
  const float* base = hin + (size_t)t*kNN*kHH;
  float d = dis[n];
  float acc = d*d*base[(size_t)n*kHH + lane];
  int e0 = offs[n], e1 = offs[n+1];
  for (int e = e0; e < e1; ++e){
    acc = fmaf(ew[e], base[(size_t)esrc[e]*kHH + lane], acc);
  }
  acc = fmaxf(acc + bias[lane], 0.f);
  size_t oi = TM ? ((size_t)t*kNN + n)*kHH + lane
                 : ((size_t)n*kTT + t)*kHH + lane;
  hout[oi] = acc;
}

// Fused LSTM layer: G = xin@Wih^T + h@Whh^T + bias, all via f16 MFMA.
// Block = 4 waves = one 16-node tile (grid 625). Wave w owns cells
// l in [16w,16w+16): its 4 N-tiles are gates i,f,g,o for those cells, so
// c/h updates are wave-local. Wih/Whh fragments register-resident (64 VGPR).
// h round-trips C-layout -> A-layout through a double-buffered 2.3KB LDS
// tile, one __syncthreads per t.
// MFMA 16x16x32 layouts (m89/m91-verified): A[m=lane&15][k=(lane>>4)*8+j],
// B[n=lane&15][k=(lane>>4)*8+j] (B^T rows), C/D[row=(lane>>4)*4+r][col=lane&15].
template<typename TI, bool LAST>
__global__ __launch_bounds__(256) void k_rec(const TI* __restrict__ xin,
                     const float* __restrict__ wih, const float* __restrict__ whh,
                     const float* __restrict__ bih, const float* __restrict__ bhh,
                     void* __restrict__ hout){
  constexpr int LP = 72;                       // LDS row pitch (halves), 144B: 16B-aligned
  __shared__ _Float16 hlds[2][16*LP];
  int tid = threadIdx.x, w = tid >> 6, lane = tid & 63;
  int lo = lane & 15, hi4 = lane >> 4;
  int nb = blockIdx.x*16;

  // Preload B fragments (W[n][k] row-major = B^T): frag[q][kt]
  half8 BI[4][2], BH[4][2];
  #pragma unroll
  for (int q = 0; q < 4; ++q){
    int row = q*kHH + w*16 + lo;
    #pragma unroll
    for (int kt = 0; kt < 2; ++kt){
      const float* pi = wih + (size_t)row*kHH + kt*32 + hi4*8;
      const float* ph = whh + (size_t)row*kHH + kt*32 + hi4*8;
      half8 fi, fh;
      #pragma unroll
      for (int j = 0; j < 8; ++j){ fi[j] = (_Float16)pi[j]; fh[j] = (_Float16)ph[j]; }
      BI[q][kt] = fi; BH[q][kt] = fh;
    }
  }
  float bias[4];
  #pragma unroll
  for (int q = 0; q < 4; ++q){
    int col = q*kHH + w*16 + lo;
    bias[q] = bih[col] + bhh[col];
  }

  float c[4] = {0.f,0.f,0.f,0.f};
  float hval[4];
  half8 ah[2];

  for (int t = 0; t < kTT; ++t){
    // xin A fragments (global; rows = nodes nb+lo)
    half8 ax[2];
    #pragma unroll
    for (int kt = 0; kt < 2; ++kt){
      const TI* p = xin + ((size_t)(nb + lo)*kTT + t)*kHH + kt*32 + hi4*8;
      if constexpr (__is_same(TI, _Float16)){
        ax[kt] = *(const half8*)p;
      } else {
        half8 f;
        #pragma unroll
        for (int j = 0; j < 8; ++j) f[j] = (_Float16)p[j];
        ax[kt] = f;
      }
    }
    floatx4 acc[4];
    #pragma unroll
    for (int q = 0; q < 4; ++q){
      floatx4 a = {0.f,0.f,0.f,0.f};
      a = __builtin_amdgcn_mfma_f32_16x16x32_f16(ax[0], BI[q][0], a, 0,0,0);
      a = __builtin_amdgcn_mfma_f32_16x16x32_f16(ax[1], BI[q][1], a, 0,0,0);
      acc[q] = a;
    }
    if (t > 0){
      #pragma unroll
      for (int q = 0; q < 4; ++q){
        floatx4 a = acc[q];
        a = __builtin_amdgcn_mfma_f32_16x16x32_f16(ah[0], BH[q][0], a, 0,0,0);
        a = __builtin_amdgcn_mfma_f32_16x16x32_f16(ah[1], BH[q][1], a, 0,0,0);
        acc[q] = a;
      }
    }
    #pragma unroll
    for (int r = 0; r < 4; ++r){
      float gi = acc[0][r] + bias[0];
      float gf = acc[1][r] + bias[1];
      float gg = acc[2][r] + bias[2];
      float go = acc[3][r] + bias[3];
      float ii = sigf(gi), ff = sigf(gf), gt = tanh_fast(gg), oo = sigf(go);
      c[r] = ff*c[r] + ii*gt;
      hval[r] = oo * tanh_fast(c[r]);
    }
    if (t < kTT-1){
      _Float16* hb = &hlds[t & 1][0];
      #pragma unroll
      for (int r = 0; r < 4; ++r)
        hb[(hi4*4 + r)*LP + w*16 + lo] = (_Float16)hval[r];
      __syncthreads();
      const _Float16* rb = &hlds[t & 1][0];
      #pragma unroll
      for (int kt = 0; kt < 2; ++kt)
        ah[kt] = *(const half8*)&rb[lo*LP + kt*32 + hi4*8];
    }
    if (!LAST){
      _Float16* ho = (_Float16*)hout;
      #pragma unroll
      for (int r = 0; r < 4; ++r)
        ho[((size_t)(nb + hi4*4 + r)*kTT + t)*kHH + w*16 + lo] = (_Float16)hval[r];
    } else if (t == kTT-1){
      float* ho = (float*)hout;
      #pragma unroll
      for (int r = 0; r < 4; ++r)
        ho[(size_t)(nb + hi4*4 + r)*kHH + w*16 + lo] = hval[r];
    }
  }
}

// FC on compact last-timestep h: h is [kNN][64] fp32
__global__ void k_fc(const float* __restrict__ h, const float* __restrict__ w,
                     const float* __restrict__ b, float* __restrict__ out){
  int tid = blockIdx.x*256 + threadIdx.x;
  if (tid >= kNN*kOUT) return;
  int n = tid / kOUT, o = tid - n*kOUT;
  const float* hp = h + (size_t)n*kHH;
  const float* wp = w + o*kHH;
  float acc = b[o];
  #pragma unroll 8
  for (int j = 0; j < kHH; ++j) acc = fmaf(hp[j], wp[j], acc);
  out[tid] = acc;
}

extern "C" void kernel_launch(void* const* d_in, const int* in_sizes, int n_in,
                              void* d_out, int out_size, void* d_ws, size_t ws_size,
                              hipStream_t stream){
  const float* x    = (const float*)d_in[0];
  const int*   ei   = (const int*)  d_in[1];
  const float* gw0  = (const float*)d_in[2];
  const float* gb0  = (const float*)d_in[3];
  const float* gw1  = (const float*)d_in[4];
  const float* gb1  = (const float*)d_in[5];
  const float* wih0 = (const float*)d_in[6];
  const float* whh0 = (const float*)d_in[7];
  const float* bih0 = (const float*)d_in[8];
  const float* bhh0 = (const float*)d_in[9];
  const float* wih1 = (const float*)d_in[10];
  const float* whh1 = (const float*)d_in[11];
  const float* bih1 = (const float*)d_in[12];
  const float* bhh1 = (const float*)d_in[13];
  const float* fcw  = (const float*)d_in[14];
  const float* fcb  = (const float*)d_in[15];
  float* out = (float*)d_out;

  char* ws = (char*)d_ws;
  size_t p = 0;
  auto carve = [&](size_t bytes)->char*{
    char* r = ws + p;
    p += (bytes + 255) & ~(size_t)255;
    return r;
  };
  int*   is64 = (int*)  carve(256);
  int*   cnt  = (int*)  carve(sizeof(int)*kNN);
  int*   cur  = (int*)  carve(sizeof(int)*kNN);
  int*   offs = (int*)  carve(sizeof(int)*(kNN+1));
  float* dis  = (float*)carve(sizeof(float)*kNN);
  int*   esrc = (int*)  carve(sizeof(int)*kNE);
  float* ew   = (float*)carve(sizeof(float)*kNE);
  float* bufA = (float*)carve(sizeof(float)*(size_t)kNN*kTT*kHH);   // 30.7MB
  float* bufB = (float*)carve(sizeof(float)*(size_t)kNN*kTT*kHH);   // 30.7MB
  (void)ws_size; (void)in_sizes; (void)n_in; (void)out_size;

  hipMemsetAsync(cnt, 0, sizeof(int)*kNN, stream);
  hipMemsetAsync(cur, 0, sizeof(int)*kNN, stream);
  k_detect <<<1, 256, 0, stream>>>(ei, is64);
  k_deg    <<<(kNE+255)/256, 256, 0, stream>>>(ei, is64, cnt);
  k_scan   <<<1, 256, 0, stream>>>(cnt, offs, dis);
  k_scatter<<<(kNE+255)/256, 256, 0, stream>>>(ei, is64, offs, cur, dis, esrc, ew);

  // GCN layer 0 (all t-major): x @ gw0 -> bufA ; aggregate+bias+relu -> bufB
  k_gemm<kFIN, kHH><<<(kNN*kTT)/64, 256, 0, stream>>>(x, gw0, bufA);
  k_agg<true> <<<(kNN*kTT)/4, 256, 0, stream>>>(bufA, bufB, gb0, dis, offs, esrc, ew);
  // GCN layer 1; agg writes node-major for the LSTM
  k_gemm<kHH, kHH><<<(kNN*kTT)/64, 256, 0, stream>>>(bufB, gw1, bufA);
  k_agg<false><<<(kNN*kTT)/4, 256, 0, stream>>>(bufA, bufB, gb1, dis, offs, esrc, ew);

  // Fused LSTM layers (no gx tensor). Layer0: fp32 in -> fp16 h-seq.
  k_rec<float,    false><<<kNN/16, 256, 0, stream>>>(bufB, wih0, whh0, bih0, bhh0, bufA);
  // Layer1: fp16 in -> fp32 compact h_last [kNN][64].
  k_rec<_Float16, true ><<<kNN/16, 256, 0, stream>>>((const _Float16*)bufA, wih1, whh1, bih1, bhh1, bufB);

  // FC on last timestep
  k_fc<<<(kNN*kOUT+255)/256, 256, 0, stream>>>(bufB, fcw, fcb, out);
}

// Round 4
// 358.514 us; speedup vs baseline: 3.8985x; 1.8819x over previous
//
#include <hip/hip_runtime.h>
#include <hip/hip_bf16.h>

constexpr int kNN  = 10000;   // nodes
constexpr int kTT  = 12;      // timesteps
constexpr int kFIN = 32;      // input features
constexpr int kHH  = 64;      // hidden
constexpr int kH4  = 256;     // 4*hidden (gates)
constexpr int kOUT = 16;      // output features
constexpr int kNE  = 160000;  // edges

typedef _Float16 half8 __attribute__((ext_vector_type(8)));
typedef _Float16 half4 __attribute__((ext_vector_type(4)));
typedef _Float16 half2t __attribute__((ext_vector_type(2)));
typedef float floatx4 __attribute__((ext_vector_type(4)));

__device__ __forceinline__ float sigf(float x){ return 1.f/(1.f+__expf(-x)); }
__device__ __forceinline__ float tanh_fast(float x){
  float xc = fminf(fmaxf(x,-30.f),30.f);
  float e = __expf(-2.f*xc);
  return (1.f-e)/(1.f+e);
}

// Detect whether edge_index arrived as int64 (JAX x64) or int32. Under int32
// the odd words are random node ids (OR != 0); under little-endian int64
// every odd word is a zero hi-word. anyf must be zeroed before launch.
__global__ void k_detect(const int* __restrict__ ei, int* __restrict__ anyf){
  int a = 0;
  for (int i = blockIdx.x*256 + threadIdx.x; i < kNE; i += gridDim.x*256)
    a |= ei[2*i+1];
  unsigned long long m = __ballot(a != 0);
  if ((threadIdx.x & 63) == 0 && m) atomicOr(anyf, 1);
}

__global__ void k_deg(const int* __restrict__ ei, const int* __restrict__ anyf,
                      int* __restrict__ cnt){
  int e = blockIdx.x*256 + threadIdx.x;
  if (e >= kNE) return;
  int c = (anyf[0]==0) ? ei[2*(kNE+e)] : ei[kNE+e];
  atomicAdd(&cnt[c], 1);
}

// Exclusive scan of in-degree counts (single block) + dis = rsqrt(deg+selfloop)
__global__ void k_scan(const int* __restrict__ cnt, int* __restrict__ offs,
                       float* __restrict__ dis){
  __shared__ int part[256];
  int tid = threadIdx.x;
  const int CH = (kNN + 255)/256;
  int lo = tid*CH, hi = min(lo+CH, kNN);
  int s = 0;
  for (int i = lo; i < hi; ++i) s += cnt[i];
  part[tid] = s;
  __syncthreads();
  if (tid == 0){
    int run = 0;
    for (int i = 0; i < 256; ++i){ int v = part[i]; part[i] = run; run += v; }
  }
  __syncthreads();
  int run = part[tid];
  for (int i = lo; i < hi; ++i){ offs[i] = run; run += cnt[i]; }
  if (hi == kNN) offs[kNN] = run;
  for (int i = tid; i < kNN; i += 256) dis[i] = rsqrtf((float)(cnt[i]+1));
}

__global__ void k_scatter(const int* __restrict__ ei, const int* __restrict__ anyf,
                          const int* __restrict__ offs, int* __restrict__ cur,
                          const float* __restrict__ dis,
                          int* __restrict__ esrc, float* __restrict__ ew){
  int e = blockIdx.x*256 + threadIdx.x;
  if (e >= kNE) return;
  int f = (anyf[0]==0);
  int r = f ? ei[2*e]         : ei[e];
  int c = f ? ei[2*(kNE+e)]   : ei[kNE+e];
  int p = offs[c] + atomicAdd(&cur[c], 1);
  esrc[p] = r;
  ew[p] = dis[r]*dis[c];
}

// Tiled GEMM: out[M,N] = in[M,K] @ W[K,N], fp32 accumulate, fp16 out.
// Rows m are t-major (m = t*kNN + n) for both in and out.
template<int K, int N, typename TI>
__global__ __launch_bounds__(256) void k_gemm(const TI* __restrict__ in,
                      const float* __restrict__ Wg,
                      _Float16* __restrict__ out){
  constexpr int COLG = N/4;           // threads across columns (4 cols each)
  constexpr int ROWG = 256/COLG;
  constexpr int MR   = 4;             // rows per thread
  constexpr int MTILE= ROWG*MR;       // 64
  constexpr int AP   = K + 4;         // padded A row (16B-aligned: K%4==0)
  __shared__ float Wl[K*N];
  __shared__ float Al[MTILE*AP];
  int tid = threadIdx.x;
  int m0 = blockIdx.x*MTILE;
  if constexpr (__is_same(TI, _Float16)){
    for (int idx = tid; idx < MTILE*K/8; idx += 256){
      int r = idx/(K/8), k8 = idx - r*(K/8);
      half8 v = *(const half8*)&in[(size_t)(m0 + r)*K + k8*8];
      float* dst = &Al[r*AP + k8*8];
      #pragma unroll
      for (int j = 0; j < 8; ++j) dst[j] = (float)v[j];
    }
  } else {
    for (int idx = tid; idx < MTILE*K/4; idx += 256){
      int r = idx/(K/4), k4 = idx - r*(K/4);
      float4 v = *(const float4*)&in[(size_t)(m0 + r)*K + k4*4];
      float* dst = &Al[r*AP + k4*4];
      dst[0]=v.x; dst[1]=v.y; dst[2]=v.z; dst[3]=v.w;
    }
  }
  for (int idx = tid; idx < K*N; idx += 256) Wl[idx] = Wg[idx];
  __syncthreads();
  int cg = tid % COLG, rg = tid / COLG;
  int c0 = cg*4, r0 = rg*MR;
  float acc[MR][4];
  #pragma unroll
  for (int r=0;r<MR;++r){acc[r][0]=0.f;acc[r][1]=0.f;acc[r][2]=0.f;acc[r][3]=0.f;}
  #pragma unroll 2
  for (int k = 0; k < K; k += 4){
    float4 wv[4];
    #pragma unroll
    for (int kk = 0; kk < 4; ++kk) wv[kk] = *(const float4*)&Wl[(k+kk)*N + c0];
    #pragma unroll
    for (int r = 0; r < MR; ++r){
      float4 a4 = *(const float4*)&Al[(r0+r)*AP + k];
      acc[r][0] = fmaf(a4.x, wv[0].x, acc[r][0]);
      acc[r][1] = fmaf(a4.x, wv[0].y, acc[r][1]);
      acc[r][2] = fmaf(a4.x, wv[0].z, acc[r][2]);
      acc[r][3] = fmaf(a4.x, wv[0].w, acc[r][3]);
      acc[r][0] = fmaf(a4.y, wv[1].x, acc[r][0]);
      acc[r][1] = fmaf(a4.y, wv[1].y, acc[r][1]);
      acc[r][2] = fmaf(a4.y, wv[1].z, acc[r][2]);
      acc[r][3] = fmaf(a4.y, wv[1].w, acc[r][3]);
      acc[r][0] = fmaf(a4.z, wv[2].x, acc[r][0]);
      acc[r][1] = fmaf(a4.z, wv[2].y, acc[r][1]);
      acc[r][2] = fmaf(a4.z, wv[2].z, acc[r][2]);
      acc[r][3] = fmaf(a4.z, wv[2].w, acc[r][3]);
      acc[r][0] = fmaf(a4.w, wv[3].x, acc[r][0]);
      acc[r][1] = fmaf(a4.w, wv[3].y, acc[r][1]);
      acc[r][2] = fmaf(a4.w, wv[3].z, acc[r][2]);
      acc[r][3] = fmaf(a4.w, wv[3].w, acc[r][3]);
    }
  }
  #pragma unroll
  for (int r = 0; r < MR; ++r){
    half4 hv;
    hv[0]=(_Float16)acc[r][0]; hv[1]=(_Float16)acc[r][1];
    hv[2]=(_Float16)acc[r][2]; hv[3]=(_Float16)acc[r][3];
    *(half4*)&out[(size_t)(m0 + r0 + r)*N + c0] = hv;
  }
}

// GCN aggregation, fp16, t-paired: wave handles (n, t, t+1). Lanes 0-31 =
// slab t (feature pair 2l,2l+1 as half2), lanes 32-63 = slab t+1 -> one
// 256B wave load covers two timesteps. 1.25MB t-slabs are L2-resident.
// Edge loop unrolled x8: 8 idx loads then 8 gathers in flight then 16 FMAs.
// out = relu(d^2*h[n] + sum w_e h[src] + b); fp32 accumulate.
// TM: t-major out (feeds gemm) else node-major (feeds LSTM).
template<bool TM>
__global__ __launch_bounds__(256) void k_agg(const _Float16* __restrict__ hin,
                     _Float16* __restrict__ hout,
                     const float* __restrict__ bias, const float* __restrict__ dis,
                     const int* __restrict__ offs, const int* __restrict__ esrc,
                     const float* __restrict__ ew){
  int wid = threadIdx.x >> 6, lane = threadIdx.x & 63;
  int gw = blockIdx.x*4 + wid;          // gw = tp*kNN + n
  int tp = gw / kNN, n = gw - tp*kNN;
  int sel = lane >> 5, fp = lane & 31;
  int t = 2*tp + sel;
  const _Float16* hb = hin + (size_t)t*kNN*kHH;
  float d = dis[n], ws = d*d;
  half2t sv = *(const half2t*)&hb[(size_t)n*kHH + 2*fp];
  float a0 = ws*(float)sv[0], a1 = ws*(float)sv[1];
  int e0 = offs[n], e1 = offs[n+1];
  int e = e0;
  for (; e + 8 <= e1; e += 8){
    int s[8]; float w[8];
    #pragma unroll
    for (int u = 0; u < 8; ++u){ s[u] = esrc[e+u]; w[u] = ew[e+u]; }
    half2t v[8];
    #pragma unroll
    for (int u = 0; u < 8; ++u) v[u] = *(const half2t*)&hb[(size_t)s[u]*kHH + 2*fp];
    #pragma unroll
    for (int u = 0; u < 8; ++u){
      a0 = fmaf(w[u], (float)v[u][0], a0);
      a1 = fmaf(w[u], (float)v[u][1], a1);
    }
  }
  for (; e < e1; ++e){
    int su = esrc[e]; float wu = ew[e];
    half2t vu = *(const half2t*)&hb[(size_t)su*kHH + 2*fp];
    a0 = fmaf(wu, (float)vu[0], a0);
    a1 = fmaf(wu, (float)vu[1], a1);
  }
  a0 = fmaxf(a0 + bias[2*fp],   0.f);
  a1 = fmaxf(a1 + bias[2*fp+1], 0.f);
  half2t o; o[0] = (_Float16)a0; o[1] = (_Float16)a1;
  size_t oi = TM ? ((size_t)t*kNN + n)*kHH + 2*fp
                 : ((size_t)n*kTT + t)*kHH + 2*fp;
  *(half2t*)&hout[oi] = o;
}

// Fused LSTM layer: G = xin@Wih^T + h@Whh^T + bias via f16 MFMA.
// Block = 4 waves = one 16-node tile. Wave w owns cells l in [16w,16w+16):
// its 4 N-tiles are gates i,f,g,o for those cells (wave-local c/h update).
// Wih/Whh fragments register-resident. h round-trips C->A layout through
// double-buffered LDS, one __syncthreads per t. xin fragment for t+1 is
// prefetched during compute of t (hides ~500cyc global latency).
// MFMA 16x16x32 layouts: A[m=lane&15][k=(lane>>4)*8+j], B^T rows same,
// C/D[row=(lane>>4)*4+r][col=lane&15].
template<bool LAST>
__global__ __launch_bounds__(256) void k_rec(const _Float16* __restrict__ xin,
                     const float* __restrict__ wih, const float* __restrict__ whh,
                     const float* __restrict__ bih, const float* __restrict__ bhh,
                     void* __restrict__ hout){
  constexpr int LP = 72;                       // LDS row pitch (halves)
  __shared__ _Float16 hlds[2][16*LP];
  int tid = threadIdx.x, w = tid >> 6, lane = tid & 63;
  int lo = lane & 15, hi4 = lane >> 4;
  int nb = blockIdx.x*16;

  half8 BI[4][2], BH[4][2];
  #pragma unroll
  for (int q = 0; q < 4; ++q){
    int row = q*kHH + w*16 + lo;
    #pragma unroll
    for (int kt = 0; kt < 2; ++kt){
      const float* pi = wih + (size_t)row*kHH + kt*32 + hi4*8;
      const float* ph = whh + (size_t)row*kHH + kt*32 + hi4*8;
      half8 fi, fh;
      #pragma unroll
      for (int j = 0; j < 8; ++j){ fi[j] = (_Float16)pi[j]; fh[j] = (_Float16)ph[j]; }
      BI[q][kt] = fi; BH[q][kt] = fh;
    }
  }
  float bias[4];
  #pragma unroll
  for (int q = 0; q < 4; ++q){
    int col = q*kHH + w*16 + lo;
    bias[q] = bih[col] + bhh[col];
  }

  float c[4] = {0.f,0.f,0.f,0.f};
  float hval[4];
  half8 ah[2], axn[2];

  const _Float16* xrow = xin + (size_t)(nb + lo)*kTT*kHH;
  #pragma unroll
  for (int kt = 0; kt < 2; ++kt) axn[kt] = *(const half8*)&xrow[kt*32 + hi4*8];

  for (int t = 0; t < kTT; ++t){
    half8 ax[2] = {axn[0], axn[1]};
    if (t < kTT-1){
      #pragma unroll
      for (int kt = 0; kt < 2; ++kt)
        axn[kt] = *(const half8*)&xrow[(size_t)(t+1)*kHH + kt*32 + hi4*8];
    }
    floatx4 acc[4];
    #pragma unroll
    for (int q = 0; q < 4; ++q){
      floatx4 a = {0.f,0.f,0.f,0.f};
      a = __builtin_amdgcn_mfma_f32_16x16x32_f16(ax[0], BI[q][0], a, 0,0,0);
      a = __builtin_amdgcn_mfma_f32_16x16x32_f16(ax[1], BI[q][1], a, 0,0,0);
      acc[q] = a;
    }
    if (t > 0){
      #pragma unroll
      for (int q = 0; q < 4; ++q){
        floatx4 a = acc[q];
        a = __builtin_amdgcn_mfma_f32_16x16x32_f16(ah[0], BH[q][0], a, 0,0,0);
        a = __builtin_amdgcn_mfma_f32_16x16x32_f16(ah[1], BH[q][1], a, 0,0,0);
        acc[q] = a;
      }
    }
    #pragma unroll
    for (int r = 0; r < 4; ++r){
      float gi = acc[0][r] + bias[0];
      float gf = acc[1][r] + bias[1];
      float gg = acc[2][r] + bias[2];
      float go = acc[3][r] + bias[3];
      float ii = sigf(gi), ff = sigf(gf), gt = tanh_fast(gg), oo = sigf(go);
      c[r] = ff*c[r] + ii*gt;
      hval[r] = oo * tanh_fast(c[r]);
    }
    if (t < kTT-1){
      _Float16* hb = &hlds[t & 1][0];
      #pragma unroll
      for (int r = 0; r < 4; ++r)
        hb[(hi4*4 + r)*LP + w*16 + lo] = (_Float16)hval[r];
      __syncthreads();
      const _Float16* rb = &hlds[t & 1][0];
      #pragma unroll
      for (int kt = 0; kt < 2; ++kt)
        ah[kt] = *(const half8*)&rb[lo*LP + kt*32 + hi4*8];
    }
    if (!LAST){
      _Float16* ho = (_Float16*)hout;
      #pragma unroll
      for (int r = 0; r < 4; ++r)
        ho[((size_t)(nb + hi4*4 + r)*kTT + t)*kHH + w*16 + lo] = (_Float16)hval[r];
    } else if (t == kTT-1){
      float* ho = (float*)hout;
      #pragma unroll
      for (int r = 0; r < 4; ++r)
        ho[(size_t)(nb + hi4*4 + r)*kHH + w*16 + lo] = hval[r];
    }
  }
}

// FC on compact last-timestep h: h is [kNN][64] fp32
__global__ void k_fc(const float* __restrict__ h, const float* __restrict__ w,
                     const float* __restrict__ b, float* __restrict__ out){
  int tid = blockIdx.x*256 + threadIdx.x;
  if (tid >= kNN*kOUT) return;
  int n = tid / kOUT, o = tid - n*kOUT;
  const float* hp = h + (size_t)n*kHH;
  const float* wp = w + o*kHH;
  float acc = b[o];
  #pragma unroll 8
  for (int j = 0; j < kHH; ++j) acc = fmaf(hp[j], wp[j], acc);
  out[tid] = acc;
}

extern "C" void kernel_launch(void* const* d_in, const int* in_sizes, int n_in,
                              void* d_out, int out_size, void* d_ws, size_t ws_size,
                              hipStream_t stream){
  const float* x    = (const float*)d_in[0];
  const int*   ei   = (const int*)  d_in[1];
  const float* gw0  = (const float*)d_in[2];
  const float* gb0  = (const float*)d_in[3];
  const float* gw1  = (const float*)d_in[4];
  const float* gb1  = (const float*)d_in[5];
  const float* wih0 = (const float*)d_in[6];
  const float* whh0 = (const float*)d_in[7];
  const float* bih0 = (const float*)d_in[8];
  const float* bhh0 = (const float*)d_in[9];
  const float* wih1 = (const float*)d_in[10];
  const float* whh1 = (const float*)d_in[11];
  const float* bih1 = (const float*)d_in[12];
  const float* bhh1 = (const float*)d_in[13];
  const float* fcw  = (const float*)d_in[14];
  const float* fcb  = (const float*)d_in[15];
  float* out = (float*)d_out;

  char* ws = (char*)d_ws;
  size_t p = 0;
  auto carve = [&](size_t bytes)->char*{
    char* r = ws + p;
    p += (bytes + 255) & ~(size_t)255;
    return r;
  };
  int*   anyf = (int*)  carve(256);
  int*   cnt  = (int*)  carve(sizeof(int)*kNN);
  int*   cur  = (int*)  carve(sizeof(int)*kNN);
  int*   offs = (int*)  carve(sizeof(int)*(kNN+1));
  float* dis  = (float*)carve(sizeof(float)*kNN);
  int*   esrc = (int*)  carve(sizeof(int)*kNE);
  float* ew   = (float*)carve(sizeof(float)*kNE);
  // fp16 intermediates: [12][10000][64] or [10000][12][64] = 15.36MB each
  _Float16* bufA = (_Float16*)carve(sizeof(_Float16)*(size_t)kNN*kTT*kHH);
  _Float16* bufB = (_Float16*)carve(sizeof(_Float16)*(size_t)kNN*kTT*kHH);
  (void)ws_size; (void)in_sizes; (void)n_in; (void)out_size;

  hipMemsetAsync(anyf, 0, 256, stream);
  hipMemsetAsync(cnt, 0, sizeof(int)*kNN, stream);
  hipMemsetAsync(cur, 0, sizeof(int)*kNN, stream);
  k_detect <<<80, 256, 0, stream>>>(ei, anyf);
  k_deg    <<<(kNE+255)/256, 256, 0, stream>>>(ei, anyf, cnt);
  k_scan   <<<1, 256, 0, stream>>>(cnt, offs, dis);
  k_scatter<<<(kNE+255)/256, 256, 0, stream>>>(ei, anyf, offs, cur, dis, esrc, ew);

  // GCN layer 0 (t-major): x @ gw0 -> bufA ; aggregate+bias+relu -> bufB
  k_gemm<kFIN, kHH, float><<<(kNN*kTT)/64, 256, 0, stream>>>(x, gw0, bufA);
  k_agg<true> <<<(kNN*kTT/2)/4, 256, 0, stream>>>(bufA, bufB, gb0, dis, offs, esrc, ew);
  // GCN layer 1; agg writes node-major for the LSTM
  k_gemm<kHH, kHH, _Float16><<<(kNN*kTT)/64, 256, 0, stream>>>(bufB, gw1, bufA);
  k_agg<false><<<(kNN*kTT/2)/4, 256, 0, stream>>>(bufA, bufB, gb1, dis, offs, esrc, ew);

  // Fused LSTM layers. Layer0: fp16 in -> fp16 h-seq (node-major).
  k_rec<false><<<kNN/16, 256, 0, stream>>>(bufB, wih0, whh0, bih0, bhh0, bufA);
  // Layer1: fp16 in -> fp32 compact h_last [kNN][64].
  k_rec<true ><<<kNN/16, 256, 0, stream>>>(bufA, wih1, whh1, bih1, bhh1, bufB);

  // FC on last timestep
  k_fc<<<(kNN*kOUT+255)/256, 256, 0, stream>>>((const float*)bufB, fcw, fcb, out);
}

// Round 5
// 343.443 us; speedup vs baseline: 4.0696x; 1.0439x over previous
//
#include <hip/hip_runtime.h>
#include <hip/hip_bf16.h>

constexpr int kNN  = 10000;   // nodes
constexpr int kTT  = 12;      // timesteps
constexpr int kFIN = 32;      // input features
constexpr int kHH  = 64;      // hidden
constexpr int kH4  = 256;     // 4*hidden (gates)
constexpr int kOUT = 16;      // output features
constexpr int kNE  = 160000;  // edges

typedef _Float16 half8 __attribute__((ext_vector_type(8)));
typedef _Float16 half4 __attribute__((ext_vector_type(4)));
typedef _Float16 half2t __attribute__((ext_vector_type(2)));
typedef float floatx4 __attribute__((ext_vector_type(4)));

__device__ __forceinline__ float sigf(float x){ return 1.f/(1.f+__expf(-x)); }
__device__ __forceinline__ float tanh_fast(float x){
  float xc = fminf(fmaxf(x,-30.f),30.f);
  float e = __expf(-2.f*xc);
  return (1.f-e)/(1.f+e);
}

// Detect whether edge_index arrived as int64 (JAX x64) or int32. Under int32
// the odd words are random node ids (OR != 0); under little-endian int64
// every odd word is a zero hi-word. anyf must be zeroed before launch.
__global__ void k_detect(const int* __restrict__ ei, int* __restrict__ anyf){
  int a = 0;
  for (int i = blockIdx.x*256 + threadIdx.x; i < kNE; i += gridDim.x*256)
    a |= ei[2*i+1];
  unsigned long long m = __ballot(a != 0);
  if ((threadIdx.x & 63) == 0 && m) atomicOr(anyf, 1);
}

__global__ void k_deg(const int* __restrict__ ei, const int* __restrict__ anyf,
                      int* __restrict__ cnt){
  int e = blockIdx.x*256 + threadIdx.x;
  if (e >= kNE) return;
  int c = (anyf[0]==0) ? ei[2*(kNE+e)] : ei[kNE+e];
  atomicAdd(&cnt[c], 1);
}

// Exclusive scan of in-degree counts (single block) + dis = rsqrt(deg+selfloop)
__global__ void k_scan(const int* __restrict__ cnt, int* __restrict__ offs,
                       float* __restrict__ dis){
  __shared__ int part[256];
  int tid = threadIdx.x;
  const int CH = (kNN + 255)/256;
  int lo = tid*CH, hi = min(lo+CH, kNN);
  int s = 0;
  for (int i = lo; i < hi; ++i) s += cnt[i];
  part[tid] = s;
  __syncthreads();
  if (tid == 0){
    int run = 0;
    for (int i = 0; i < 256; ++i){ int v = part[i]; part[i] = run; run += v; }
  }
  __syncthreads();
  int run = part[tid];
  for (int i = lo; i < hi; ++i){ offs[i] = run; run += cnt[i]; }
  if (hi == kNN) offs[kNN] = run;
  for (int i = tid; i < kNN; i += 256) dis[i] = rsqrtf((float)(cnt[i]+1));
}

__global__ void k_scatter(const int* __restrict__ ei, const int* __restrict__ anyf,
                          const int* __restrict__ offs, int* __restrict__ cur,
                          const float* __restrict__ dis,
                          int* __restrict__ esrc, float* __restrict__ ew){
  int e = blockIdx.x*256 + threadIdx.x;
  if (e >= kNE) return;
  int f = (anyf[0]==0);
  int r = f ? ei[2*e]         : ei[e];
  int c = f ? ei[2*(kNE+e)]   : ei[kNE+e];
  int p = offs[c] + atomicAdd(&cur[c], 1);
  esrc[p] = r;
  ew[p] = dis[r]*dis[c];
}

// Tiled GEMM: out[M,N] = in[M,K] @ W[K,N], fp32 accumulate, fp16 out.
// Rows m are t-major (m = t*kNN + n) for both in and out.
template<int K, int N, typename TI>
__global__ __launch_bounds__(256) void k_gemm(const TI* __restrict__ in,
                      const float* __restrict__ Wg,
                      _Float16* __restrict__ out){
  constexpr int COLG = N/4;           // threads across columns (4 cols each)
  constexpr int ROWG = 256/COLG;
  constexpr int MR   = 4;             // rows per thread
  constexpr int MTILE= ROWG*MR;       // 64
  constexpr int AP   = K + 4;         // padded A row (16B-aligned: K%4==0)
  __shared__ float Wl[K*N];
  __shared__ float Al[MTILE*AP];
  int tid = threadIdx.x;
  int m0 = blockIdx.x*MTILE;
  if constexpr (__is_same(TI, _Float16)){
    for (int idx = tid; idx < MTILE*K/8; idx += 256){
      int r = idx/(K/8), k8 = idx - r*(K/8);
      half8 v = *(const half8*)&in[(size_t)(m0 + r)*K + k8*8];
      float* dst = &Al[r*AP + k8*8];
      #pragma unroll
      for (int j = 0; j < 8; ++j) dst[j] = (float)v[j];
    }
  } else {
    for (int idx = tid; idx < MTILE*K/4; idx += 256){
      int r = idx/(K/4), k4 = idx - r*(K/4);
      float4 v = *(const float4*)&in[(size_t)(m0 + r)*K + k4*4];
      float* dst = &Al[r*AP + k4*4];
      dst[0]=v.x; dst[1]=v.y; dst[2]=v.z; dst[3]=v.w;
    }
  }
  for (int idx = tid; idx < K*N; idx += 256) Wl[idx] = Wg[idx];
  __syncthreads();
  int cg = tid % COLG, rg = tid / COLG;
  int c0 = cg*4, r0 = rg*MR;
  float acc[MR][4];
  #pragma unroll
  for (int r=0;r<MR;++r){acc[r][0]=0.f;acc[r][1]=0.f;acc[r][2]=0.f;acc[r][3]=0.f;}
  #pragma unroll 2
  for (int k = 0; k < K; k += 4){
    float4 wv[4];
    #pragma unroll
    for (int kk = 0; kk < 4; ++kk) wv[kk] = *(const float4*)&Wl[(k+kk)*N + c0];
    #pragma unroll
    for (int r = 0; r < MR; ++r){
      float4 a4 = *(const float4*)&Al[(r0+r)*AP + k];
      acc[r][0] = fmaf(a4.x, wv[0].x, acc[r][0]);
      acc[r][1] = fmaf(a4.x, wv[0].y, acc[r][1]);
      acc[r][2] = fmaf(a4.x, wv[0].z, acc[r][2]);
      acc[r][3] = fmaf(a4.x, wv[0].w, acc[r][3]);
      acc[r][0] = fmaf(a4.y, wv[1].x, acc[r][0]);
      acc[r][1] = fmaf(a4.y, wv[1].y, acc[r][1]);
      acc[r][2] = fmaf(a4.y, wv[1].z, acc[r][2]);
      acc[r][3] = fmaf(a4.y, wv[1].w, acc[r][3]);
      acc[r][0] = fmaf(a4.z, wv[2].x, acc[r][0]);
      acc[r][1] = fmaf(a4.z, wv[2].y, acc[r][1]);
      acc[r][2] = fmaf(a4.z, wv[2].z, acc[r][2]);
      acc[r][3] = fmaf(a4.z, wv[2].w, acc[r][3]);
      acc[r][0] = fmaf(a4.w, wv[3].x, acc[r][0]);
      acc[r][1] = fmaf(a4.w, wv[3].y, acc[r][1]);
      acc[r][2] = fmaf(a4.w, wv[3].z, acc[r][2]);
      acc[r][3] = fmaf(a4.w, wv[3].w, acc[r][3]);
    }
  }
  #pragma unroll
  for (int r = 0; r < MR; ++r){
    half4 hv;
    hv[0]=(_Float16)acc[r][0]; hv[1]=(_Float16)acc[r][1];
    hv[2]=(_Float16)acc[r][2]; hv[3]=(_Float16)acc[r][3];
    *(half4*)&out[(size_t)(m0 + r0 + r)*N + c0] = hv;
  }
}

// GCN aggregation, fp16, t-paired: wave handles (n, t, t+1). Lanes 0-31 =
// slab t (feature pair 2l,2l+1 as half2), lanes 32-63 = slab t+1 -> one
// 256B wave load covers two timesteps. 1.25MB t-slabs are L2-resident.
// Edge loop unrolled x8. out = relu(d^2*h[n] + sum w_e h[src] + b); fp32 acc.
// TM: t-major out (feeds gemm) else node-major (feeds LSTM).
template<bool TM>
__global__ __launch_bounds__(256) void k_agg(const _Float16* __restrict__ hin,
                     _Float16* __restrict__ hout,
                     const float* __restrict__ bias, const float* __restrict__ dis,
                     const int* __restrict__ offs, const int* __restrict__ esrc,
                     const float* __restrict__ ew){
  int wid = threadIdx.x >> 6, lane = threadIdx.x & 63;
  int gw = blockIdx.x*4 + wid;          // gw = tp*kNN + n
  int tp = gw / kNN, n = gw - tp*kNN;
  int sel = lane >> 5, fp = lane & 31;
  int t = 2*tp + sel;
  const _Float16* hb = hin + (size_t)t*kNN*kHH;
  float d = dis[n], ws = d*d;
  half2t sv = *(const half2t*)&hb[(size_t)n*kHH + 2*fp];
  float a0 = ws*(float)sv[0], a1 = ws*(float)sv[1];
  int e0 = offs[n], e1 = offs[n+1];
  int e = e0;
  for (; e + 8 <= e1; e += 8){
    int s[8]; float w[8];
    #pragma unroll
    for (int u = 0; u < 8; ++u){ s[u] = esrc[e+u]; w[u] = ew[e+u]; }
    half2t v[8];
    #pragma unroll
    for (int u = 0; u < 8; ++u) v[u] = *(const half2t*)&hb[(size_t)s[u]*kHH + 2*fp];
    #pragma unroll
    for (int u = 0; u < 8; ++u){
      a0 = fmaf(w[u], (float)v[u][0], a0);
      a1 = fmaf(w[u], (float)v[u][1], a1);
    }
  }
  for (; e < e1; ++e){
    int su = esrc[e]; float wu = ew[e];
    half2t vu = *(const half2t*)&hb[(size_t)su*kHH + 2*fp];
    a0 = fmaf(wu, (float)vu[0], a0);
    a1 = fmaf(wu, (float)vu[1], a1);
  }
  a0 = fmaxf(a0 + bias[2*fp],   0.f);
  a1 = fmaxf(a1 + bias[2*fp+1], 0.f);
  half2t o; o[0] = (_Float16)a0; o[1] = (_Float16)a1;
  size_t oi = TM ? ((size_t)t*kNN + n)*kHH + 2*fp
                 : ((size_t)n*kTT + t)*kHH + 2*fp;
  *(half2t*)&hout[oi] = o;
}

// Fused 2-layer LSTM + FC. Block = 512 threads = 8 waves = one 16-node tile.
// Waves 0-3: layer 0 (wave wl owns gate-slice cells 16wl..16wl+16).
// Waves 4-7: layer 1, software-pipelined one timestep behind, consuming
// h0(t) straight from the same double-buffered LDS tile layer 0 uses for
// its own C->A layout roundtrip. One barrier per pipeline stage (13 stages).
// Layer-1 h-seq never touches HBM; after the loop wave 4 computes
// out = h1(11) @ fcw^T + fcb with 2 MFMAs.
// MFMA 16x16x32 layouts: A[m=lane&15][k=(lane>>4)*8+j], B^T rows same,
// C/D[row=(lane>>4)*4+r][col=lane&15].
// Double-buffer safety: writes at stage i+1 target buf[(i+1)&1] while the
// slowest wave reads buf[i&1] (and stage i+2 is fenced by barrier i+1).
__global__ __launch_bounds__(512) void k_rec2(const _Float16* __restrict__ xin,
                     const float* __restrict__ wih0, const float* __restrict__ whh0,
                     const float* __restrict__ bih0, const float* __restrict__ bhh0,
                     const float* __restrict__ wih1, const float* __restrict__ whh1,
                     const float* __restrict__ bih1, const float* __restrict__ bhh1,
                     const float* __restrict__ fcw, const float* __restrict__ fcb,
                     float* __restrict__ out){
  constexpr int LP = 72;                       // LDS row pitch (halves)
  __shared__ _Float16 h0b[2][16*LP];
  __shared__ _Float16 h1b[2][16*LP];
  int tid = threadIdx.x, w = tid >> 6, lane = tid & 63;
  int lo = lane & 15, hi4 = lane >> 4;
  int layer = w >> 2, wl = w & 3;
  int nb = blockIdx.x*16;

  const float* wih = layer ? wih1 : wih0;
  const float* whh = layer ? whh1 : whh0;
  const float* bi_ = layer ? bih1 : bih0;
  const float* bh_ = layer ? bhh1 : bhh0;

  half8 BI[4][2], BH[4][2];
  #pragma unroll
  for (int q = 0; q < 4; ++q){
    int row = q*kHH + wl*16 + lo;
    #pragma unroll
    for (int kt = 0; kt < 2; ++kt){
      const float* pi = wih + (size_t)row*kHH + kt*32 + hi4*8;
      const float* ph = whh + (size_t)row*kHH + kt*32 + hi4*8;
      half8 fi, fh;
      #pragma unroll
      for (int j = 0; j < 8; ++j){ fi[j] = (_Float16)pi[j]; fh[j] = (_Float16)ph[j]; }
      BI[q][kt] = fi; BH[q][kt] = fh;
    }
  }
  float bias[4];
  #pragma unroll
  for (int q = 0; q < 4; ++q){
    int col = q*kHH + wl*16 + lo;
    bias[q] = bi_[col] + bh_[col];
  }
  // FC B-frags (used by wave 4 only): B[n=o][k=j] = fcw[o][j], o = lo < 16
  half8 FW[2];
  if (w == 4){
    #pragma unroll
    for (int kt = 0; kt < 2; ++kt){
      const float* pf = fcw + (size_t)lo*kHH + kt*32 + hi4*8;
      half8 f;
      #pragma unroll
      for (int j = 0; j < 8; ++j) f[j] = (_Float16)pf[j];
      FW[kt] = f;
    }
  }

  float c[4] = {0.f,0.f,0.f,0.f};
  half8 ax[2], ah[2], axn[2];

  const _Float16* xrow = xin + (size_t)(nb + lo)*kTT*kHH;
  if (layer == 0){
    #pragma unroll
    for (int kt = 0; kt < 2; ++kt) axn[kt] = *(const half8*)&xrow[kt*32 + hi4*8];
  }

  for (int i = 0; i < 13; ++i){
    int t = layer ? i-1 : i;
    bool act = layer ? (i >= 1) : (i < 12);
    if (act){
      if (layer == 0){
        ax[0] = axn[0]; ax[1] = axn[1];
        if (t < kTT-1){
          #pragma unroll
          for (int kt = 0; kt < 2; ++kt)
            axn[kt] = *(const half8*)&xrow[(size_t)(t+1)*kHH + kt*32 + hi4*8];
        }
      }
      floatx4 acc[4];
      #pragma unroll
      for (int q = 0; q < 4; ++q){
        floatx4 a = {0.f,0.f,0.f,0.f};
        a = __builtin_amdgcn_mfma_f32_16x16x32_f16(ax[0], BI[q][0], a, 0,0,0);
        a = __builtin_amdgcn_mfma_f32_16x16x32_f16(ax[1], BI[q][1], a, 0,0,0);
        acc[q] = a;
      }
      if (t > 0){
        #pragma unroll
        for (int q = 0; q < 4; ++q){
          floatx4 a = acc[q];
          a = __builtin_amdgcn_mfma_f32_16x16x32_f16(ah[0], BH[q][0], a, 0,0,0);
          a = __builtin_amdgcn_mfma_f32_16x16x32_f16(ah[1], BH[q][1], a, 0,0,0);
          acc[q] = a;
        }
      }
      _Float16* hb = layer ? &h1b[t & 1][0] : &h0b[t & 1][0];
      #pragma unroll
      for (int r = 0; r < 4; ++r){
        float gi = acc[0][r] + bias[0];
        float gf = acc[1][r] + bias[1];
        float gg = acc[2][r] + bias[2];
        float go = acc[3][r] + bias[3];
        float ii = sigf(gi), ff = sigf(gf), gt = tanh_fast(gg), oo = sigf(go);
        c[r] = ff*c[r] + ii*gt;
        float hn = oo * tanh_fast(c[r]);
        hb[(hi4*4 + r)*LP + wl*16 + lo] = (_Float16)hn;
      }
    }
    __syncthreads();
    if (layer == 0){
      if (i < 11){
        const _Float16* rb = &h0b[i & 1][0];
        #pragma unroll
        for (int kt = 0; kt < 2; ++kt)
          ah[kt] = *(const half8*)&rb[lo*LP + kt*32 + hi4*8];
      }
    } else {
      if (i < 12){
        const _Float16* rb = &h0b[i & 1][0];
        #pragma unroll
        for (int kt = 0; kt < 2; ++kt)
          ax[kt] = *(const half8*)&rb[lo*LP + kt*32 + hi4*8];
      }
      if (i >= 1 && i < 12){
        const _Float16* rb = &h1b[(i-1) & 1][0];
        #pragma unroll
        for (int kt = 0; kt < 2; ++kt)
          ah[kt] = *(const half8*)&rb[lo*LP + kt*32 + hi4*8];
      }
    }
  }
  // FC: h1(t=11) sits in h1b[1] (barrier at stage 12 already passed)
  if (w == 4){
    const _Float16* rb = &h1b[1][0];
    half8 a0 = *(const half8*)&rb[lo*LP + 0*32 + hi4*8];
    half8 a1 = *(const half8*)&rb[lo*LP + 1*32 + hi4*8];
    floatx4 a = {0.f,0.f,0.f,0.f};
    a = __builtin_amdgcn_mfma_f32_16x16x32_f16(a0, FW[0], a, 0,0,0);
    a = __builtin_amdgcn_mfma_f32_16x16x32_f16(a1, FW[1], a, 0,0,0);
    float bo = fcb[lo];
    #pragma unroll
    for (int r = 0; r < 4; ++r)
      out[(size_t)(nb + hi4*4 + r)*kOUT + lo] = a[r] + bo;
  }
}

extern "C" void kernel_launch(void* const* d_in, const int* in_sizes, int n_in,
                              void* d_out, int out_size, void* d_ws, size_t ws_size,
                              hipStream_t stream){
  const float* x    = (const float*)d_in[0];
  const int*   ei   = (const int*)  d_in[1];
  const float* gw0  = (const float*)d_in[2];
  const float* gb0  = (const float*)d_in[3];
  const float* gw1  = (const float*)d_in[4];
  const float* gb1  = (const float*)d_in[5];
  const float* wih0 = (const float*)d_in[6];
  const float* whh0 = (const float*)d_in[7];
  const float* bih0 = (const float*)d_in[8];
  const float* bhh0 = (const float*)d_in[9];
  const float* wih1 = (const float*)d_in[10];
  const float* whh1 = (const float*)d_in[11];
  const float* bih1 = (const float*)d_in[12];
  const float* bhh1 = (const float*)d_in[13];
  const float* fcw  = (const float*)d_in[14];
  const float* fcb  = (const float*)d_in[15];
  float* out = (float*)d_out;

  char* ws = (char*)d_ws;
  size_t p = 0;
  auto carve = [&](size_t bytes)->char*{
    char* r = ws + p;
    p += (bytes + 255) & ~(size_t)255;
    return r;
  };
  // anyf, cnt, cur carved contiguously -> single memset clears all three
  int*   anyf = (int*)  carve(256);
  int*   cnt  = (int*)  carve(sizeof(int)*kNN);
  int*   cur  = (int*)  carve(sizeof(int)*kNN);
  size_t zbytes = p;
  int*   offs = (int*)  carve(sizeof(int)*(kNN+1));
  float* dis  = (float*)carve(sizeof(float)*kNN);
  int*   esrc = (int*)  carve(sizeof(int)*kNE);
  float* ew   = (float*)carve(sizeof(float)*kNE);
  // fp16 intermediates: [12][10000][64] or [10000][12][64] = 15.36MB each
  _Float16* bufA = (_Float16*)carve(sizeof(_Float16)*(size_t)kNN*kTT*kHH);
  _Float16* bufB = (_Float16*)carve(sizeof(_Float16)*(size_t)kNN*kTT*kHH);
  (void)ws_size; (void)in_sizes; (void)n_in; (void)out_size;

  hipMemsetAsync(ws, 0, zbytes, stream);
  k_detect <<<80, 256, 0, stream>>>(ei, anyf);
  k_deg    <<<(kNE+255)/256, 256, 0, stream>>>(ei, anyf, cnt);
  k_scan   <<<1, 256, 0, stream>>>(cnt, offs, dis);
  k_scatter<<<(kNE+255)/256, 256, 0, stream>>>(ei, anyf, offs, cur, dis, esrc, ew);

  // GCN layer 0 (t-major): x @ gw0 -> bufA ; aggregate+bias+relu -> bufB
  k_gemm<kFIN, kHH, float><<<(kNN*kTT)/64, 256, 0, stream>>>(x, gw0, bufA);
  k_agg<true> <<<(kNN*kTT/2)/4, 256, 0, stream>>>(bufA, bufB, gb0, dis, offs, esrc, ew);
  // GCN layer 1; agg writes node-major for the LSTM
  k_gemm<kHH, kHH, _Float16><<<(kNN*kTT)/64, 256, 0, stream>>>(bufB, gw1, bufA);
  k_agg<false><<<(kNN*kTT/2)/4, 256, 0, stream>>>(bufA, bufB, gb1, dis, offs, esrc, ew);

  // Fused 2-layer LSTM + FC -> out
  k_rec2<<<kNN/16, 512, 0, stream>>>(bufB, wih0, whh0, bih0, bhh0,
                                     wih1, whh1, bih1, bhh1, fcw, fcb, out);
}

// Round 6
// 328.332 us; speedup vs baseline: 4.2569x; 1.0460x over previous
//
#include <hip/hip_runtime.h>
#include <hip/hip_bf16.h>

constexpr int kNN  = 10000;   // nodes
constexpr int kTT  = 12;      // timesteps
constexpr int kFIN = 32;      // input features
constexpr int kHH  = 64;      // hidden
constexpr int kH4  = 256;     // 4*hidden (gates)
constexpr int kOUT = 16;      // output features
constexpr int kNE  = 160000;  // edges

typedef _Float16 half8 __attribute__((ext_vector_type(8)));
typedef _Float16 half4 __attribute__((ext_vector_type(4)));
typedef _Float16 half2t __attribute__((ext_vector_type(2)));
typedef float floatx4 __attribute__((ext_vector_type(4)));

__device__ __forceinline__ float sigf(float x){ return 1.f/(1.f+__expf(-x)); }
__device__ __forceinline__ float tanh_fast(float x){
  float xc = fminf(fmaxf(x,-30.f),30.f);
  float e = __expf(-2.f*xc);
  return (1.f-e)/(1.f+e);
}

// int64-vs-int32 edge_index detection (odd words all zero <=> int64) fused
// with the x fp32 -> fp16 cast (independent elementwise work, saves a launch).
__global__ void k_detect_cast(const int* __restrict__ ei, int* __restrict__ anyf,
                              const float* __restrict__ x, _Float16* __restrict__ xh){
  int a = 0;
  for (int i = blockIdx.x*256 + threadIdx.x; i < kNE; i += gridDim.x*256)
    a |= ei[2*i+1];
  unsigned long long m = __ballot(a != 0);
  if ((threadIdx.x & 63) == 0 && m) atomicOr(anyf, 1);
  const int NV = kNN*kTT*kFIN/4;
  for (int i = blockIdx.x*256 + threadIdx.x; i < NV; i += gridDim.x*256){
    float4 v = *(const float4*)&x[4*i];
    half4 h;
    h[0]=(_Float16)v.x; h[1]=(_Float16)v.y; h[2]=(_Float16)v.z; h[3]=(_Float16)v.w;
    *(half4*)&xh[4*i] = h;
  }
}

__global__ void k_deg(const int* __restrict__ ei, const int* __restrict__ anyf,
                      int* __restrict__ cnt){
  int e = blockIdx.x*256 + threadIdx.x;
  if (e >= kNE) return;
  int c = (anyf[0]==0) ? ei[2*(kNE+e)] : ei[kNE+e];
  atomicAdd(&cnt[c], 1);
}

// Exclusive scan of in-degree (single block, shuffle-based partial scan)
// + dis = rsqrt(deg+selfloop)
__global__ void k_scan(const int* __restrict__ cnt, int* __restrict__ offs,
                       float* __restrict__ dis){
  __shared__ int wsum[4];
  int tid = threadIdx.x;
  const int CH = (kNN + 255)/256;
  int lo = tid*CH, hi = min(lo+CH, kNN);
  int s = 0;
  for (int i = lo; i < hi; ++i) s += cnt[i];
  int orig = s;
  int lane = tid & 63, wv = tid >> 6;
  #pragma unroll
  for (int d = 1; d < 64; d <<= 1){
    int v = __shfl_up(s, d, 64);
    if (lane >= d) s += v;
  }
  if (lane == 63) wsum[wv] = s;
  __syncthreads();
  int add = 0;
  for (int k2 = 0; k2 < wv; ++k2) add += wsum[k2];
  int run = s - orig + add;          // exclusive prefix for this thread's chunk
  for (int i = lo; i < hi; ++i){ offs[i] = run; run += cnt[i]; }
  if (hi == kNN) offs[kNN] = run;
  for (int i = tid; i < kNN; i += 256) dis[i] = rsqrtf((float)(cnt[i]+1));
}

// CSR scatter; packs (src, weight) into one int2 per edge (single scalar
// load per edge in k_agg).
__global__ void k_scatter(const int* __restrict__ ei, const int* __restrict__ anyf,
                          const int* __restrict__ offs, int* __restrict__ cur,
                          const float* __restrict__ dis,
                          int2* __restrict__ edat){
  int e = blockIdx.x*256 + threadIdx.x;
  if (e >= kNE) return;
  int f = (anyf[0]==0);
  int r = f ? ei[2*e]         : ei[e];
  int c = f ? ei[2*(kNE+e)]   : ei[kNE+e];
  int p = offs[c] + atomicAdd(&cur[c], 1);
  edat[p] = make_int2(r, __float_as_int(dis[r]*dis[c]));
}

// Pure GCN aggregation (no bias/relu — GEMM epilogue handles those since
// A_hat(xW) = (A_hat x)W). F features fp16; wave covers (n, 64/(F/2)
// timesteps); t-major in/out so each t-slab is L2-resident.
// Edge walk is scalar (readfirstlane'd bounds, uniform int2 loads), 8x unroll.
template<int F>
__global__ __launch_bounds__(256) void k_agg(const _Float16* __restrict__ hin,
                     _Float16* __restrict__ hout,
                     const float* __restrict__ dis,
                     const int* __restrict__ offs, const int2* __restrict__ edat){
  constexpr int LPF = F/2;            // lanes per timestep
  constexpr int TPW = 64/LPF;         // timesteps per wave
  int wid = threadIdx.x >> 6, lane = threadIdx.x & 63;
  int gw = blockIdx.x*4 + wid;        // gw = tq*kNN + n
  int tq = gw / kNN, n = gw - tq*kNN;
  int fp = lane & (LPF-1), tsub = lane / LPF;
  int t = TPW*tq + tsub;
  const _Float16* hb = hin + (size_t)t*kNN*F;
  float d = dis[n], ws = d*d;
  half2t sv = *(const half2t*)&hb[(size_t)n*F + 2*fp];
  float a0 = ws*(float)sv[0], a1 = ws*(float)sv[1];
  int e0 = __builtin_amdgcn_readfirstlane(offs[n]);
  int e1 = __builtin_amdgcn_readfirstlane(offs[n+1]);
  int e = e0;
  for (; e + 8 <= e1; e += 8){
    int2 d8[8];
    #pragma unroll
    for (int u = 0; u < 8; ++u) d8[u] = edat[e+u];
    half2t v[8];
    #pragma unroll
    for (int u = 0; u < 8; ++u) v[u] = *(const half2t*)&hb[(size_t)d8[u].x*F + 2*fp];
    #pragma unroll
    for (int u = 0; u < 8; ++u){
      float wu = __int_as_float(d8[u].y);
      a0 = fmaf(wu, (float)v[u][0], a0);
      a1 = fmaf(wu, (float)v[u][1], a1);
    }
  }
  for (; e < e1; ++e){
    int2 du = edat[e];
    float wu = __int_as_float(du.y);
    half2t vu = *(const half2t*)&hb[(size_t)du.x*F + 2*fp];
    a0 = fmaf(wu, (float)vu[0], a0);
    a1 = fmaf(wu, (float)vu[1], a1);
  }
  half2t o; o[0] = (_Float16)a0; o[1] = (_Float16)a1;
  *(half2t*)&hout[((size_t)t*kNN + n)*F + 2*fp] = o;
}

// Tiled GEMM: out[M,N] = relu(in[M,K] @ W[K,N] + bias), fp16 in/out, fp32 acc.
// Rows m are t-major (m = t*kNN + n). NM: store node-major ((n*T+t)*N).
template<int K, int N, bool NM>
__global__ __launch_bounds__(256) void k_gemm(const _Float16* __restrict__ in,
                      const float* __restrict__ Wg, const float* __restrict__ bias,
                      _Float16* __restrict__ out){
  constexpr int COLG = N/4;
  constexpr int ROWG = 256/COLG;
  constexpr int MR   = 4;
  constexpr int MTILE= ROWG*MR;       // 64
  constexpr int AP   = K + 4;
  __shared__ float Wl[K*N];
  __shared__ float Al[MTILE*AP];
  int tid = threadIdx.x;
  int m0 = blockIdx.x*MTILE;
  for (int idx = tid; idx < MTILE*K/8; idx += 256){
    int r = idx/(K/8), k8 = idx - r*(K/8);
    half8 v = *(const half8*)&in[(size_t)(m0 + r)*K + k8*8];
    float* dst = &Al[r*AP + k8*8];
    #pragma unroll
    for (int j = 0; j < 8; ++j) dst[j] = (float)v[j];
  }
  for (int idx = tid; idx < K*N; idx += 256) Wl[idx] = Wg[idx];
  __syncthreads();
  int cg = tid % COLG, rg = tid / COLG;
  int c0 = cg*4, r0 = rg*MR;
  float acc[MR][4];
  #pragma unroll
  for (int r=0;r<MR;++r){acc[r][0]=0.f;acc[r][1]=0.f;acc[r][2]=0.f;acc[r][3]=0.f;}
  #pragma unroll 2
  for (int k = 0; k < K; k += 4){
    float4 wv[4];
    #pragma unroll
    for (int kk = 0; kk < 4; ++kk) wv[kk] = *(const float4*)&Wl[(k+kk)*N + c0];
    #pragma unroll
    for (int r = 0; r < MR; ++r){
      float4 a4 = *(const float4*)&Al[(r0+r)*AP + k];
      acc[r][0] = fmaf(a4.x, wv[0].x, acc[r][0]);
      acc[r][1] = fmaf(a4.x, wv[0].y, acc[r][1]);
      acc[r][2] = fmaf(a4.x, wv[0].z, acc[r][2]);
      acc[r][3] = fmaf(a4.x, wv[0].w, acc[r][3]);
      acc[r][0] = fmaf(a4.y, wv[1].x, acc[r][0]);
      acc[r][1] = fmaf(a4.y, wv[1].y, acc[r][1]);
      acc[r][2] = fmaf(a4.y, wv[1].z, acc[r][2]);
      acc[r][3] = fmaf(a4.y, wv[1].w, acc[r][3]);
      acc[r][0] = fmaf(a4.z, wv[2].x, acc[r][0]);
      acc[r][1] = fmaf(a4.z, wv[2].y, acc[r][1]);
      acc[r][2] = fmaf(a4.z, wv[2].z, acc[r][2]);
      acc[r][3] = fmaf(a4.z, wv[2].w, acc[r][3]);
      acc[r][0] = fmaf(a4.w, wv[3].x, acc[r][0]);
      acc[r][1] = fmaf(a4.w, wv[3].y, acc[r][1]);
      acc[r][2] = fmaf(a4.w, wv[3].z, acc[r][2]);
      acc[r][3] = fmaf(a4.w, wv[3].w, acc[r][3]);
    }
  }
  float4 bb = *(const float4*)&bias[c0];
  #pragma unroll
  for (int r = 0; r < MR; ++r){
    half4 hv;
    hv[0]=(_Float16)fmaxf(acc[r][0]+bb.x, 0.f);
    hv[1]=(_Float16)fmaxf(acc[r][1]+bb.y, 0.f);
    hv[2]=(_Float16)fmaxf(acc[r][2]+bb.z, 0.f);
    hv[3]=(_Float16)fmaxf(acc[r][3]+bb.w, 0.f);
    int m = m0 + r0 + r;
    size_t oi;
    if (NM){ int t = m/kNN, n = m - t*kNN; oi = ((size_t)n*kTT + t)*N + c0; }
    else    oi = (size_t)m*N + c0;
    *(half4*)&out[oi] = hv;
  }
}

// Fused 2-layer LSTM + FC, TWO independent 16-node tiles per block (same
// register-resident weight fragments feed both A-streams -> 2x work between
// barriers, latency of tile0's epilogue hidden under tile1's MFMAs).
// Block = 512 thr = 8 waves; waves 0-3 layer0, 4-7 layer1 one t behind,
// h exchanged through per-tile double-buffered LDS. Waves 4,5 finish with
// the FC on tiles 0,1.
__global__ __launch_bounds__(512) void k_rec2(const _Float16* __restrict__ xin,
                     const float* __restrict__ wih0, const float* __restrict__ whh0,
                     const float* __restrict__ bih0, const float* __restrict__ bhh0,
                     const float* __restrict__ wih1, const float* __restrict__ whh1,
                     const float* __restrict__ bih1, const float* __restrict__ bhh1,
                     const float* __restrict__ fcw, const float* __restrict__ fcb,
                     float* __restrict__ out){
  constexpr int LP = 72;                       // LDS row pitch (halves)
  __shared__ _Float16 h0b[2][2][16*LP];        // [tile][dbuf]
  __shared__ _Float16 h1b[2][2][16*LP];
  int tid = threadIdx.x, w = tid >> 6, lane = tid & 63;
  int lo = lane & 15, hi4 = lane >> 4;
  int layer = w >> 2, wl = w & 3;
  int nb0 = blockIdx.x*32;

  const float* wih = layer ? wih1 : wih0;
  const float* whh = layer ? whh1 : whh0;
  const float* bi_ = layer ? bih1 : bih0;
  const float* bh_ = layer ? bhh1 : bhh0;

  half8 BI[4][2], BH[4][2];
  #pragma unroll
  for (int q = 0; q < 4; ++q){
    int row = q*kHH + wl*16 + lo;
    #pragma unroll
    for (int kt = 0; kt < 2; ++kt){
      const float* pi = wih + (size_t)row*kHH + kt*32 + hi4*8;
      const float* ph = whh + (size_t)row*kHH + kt*32 + hi4*8;
      half8 fi, fh;
      #pragma unroll
      for (int j = 0; j < 8; ++j){ fi[j] = (_Float16)pi[j]; fh[j] = (_Float16)ph[j]; }
      BI[q][kt] = fi; BH[q][kt] = fh;
    }
  }
  float bias[4];
  #pragma unroll
  for (int q = 0; q < 4; ++q){
    int col = q*kHH + wl*16 + lo;
    bias[q] = bi_[col] + bh_[col];
  }
  half8 FW[2];
  if (w == 4 || w == 5){
    #pragma unroll
    for (int kt = 0; kt < 2; ++kt){
      const float* pf = fcw + (size_t)lo*kHH + kt*32 + hi4*8;
      half8 f;
      #pragma unroll
      for (int j = 0; j < 8; ++j) f[j] = (_Float16)pf[j];
      FW[kt] = f;
    }
  }

  float c[2][4];
  #pragma unroll
  for (int u = 0; u < 2; ++u){c[u][0]=0.f;c[u][1]=0.f;c[u][2]=0.f;c[u][3]=0.f;}
  half8 ax[2][2], ah[2][2], axn[2][2];

  const _Float16* xrow[2];
  #pragma unroll
  for (int u = 0; u < 2; ++u)
    xrow[u] = xin + (size_t)min(nb0 + u*16 + lo, kNN-1)*kTT*kHH;
  if (layer == 0){
    #pragma unroll
    for (int u = 0; u < 2; ++u)
      #pragma unroll
      for (int kt = 0; kt < 2; ++kt)
        axn[u][kt] = *(const half8*)&xrow[u][kt*32 + hi4*8];
  }

  for (int i = 0; i < 13; ++i){
    int t = layer ? i-1 : i;
    bool act = layer ? (i >= 1) : (i < 12);
    if (act){
      #pragma unroll
      for (int u = 0; u < 2; ++u){
        if (layer == 0){
          ax[u][0] = axn[u][0]; ax[u][1] = axn[u][1];
          if (t < kTT-1){
            #pragma unroll
            for (int kt = 0; kt < 2; ++kt)
              axn[u][kt] = *(const half8*)&xrow[u][(size_t)(t+1)*kHH + kt*32 + hi4*8];
          }
        }
        floatx4 acc[4];
        #pragma unroll
        for (int q = 0; q < 4; ++q){
          floatx4 a = {0.f,0.f,0.f,0.f};
          a = __builtin_amdgcn_mfma_f32_16x16x32_f16(ax[u][0], BI[q][0], a, 0,0,0);
          a = __builtin_amdgcn_mfma_f32_16x16x32_f16(ax[u][1], BI[q][1], a, 0,0,0);
          acc[q] = a;
        }
        if (t > 0){
          #pragma unroll
          for (int q = 0; q < 4; ++q){
            floatx4 a = acc[q];
            a = __builtin_amdgcn_mfma_f32_16x16x32_f16(ah[u][0], BH[q][0], a, 0,0,0);
            a = __builtin_amdgcn_mfma_f32_16x16x32_f16(ah[u][1], BH[q][1], a, 0,0,0);
            acc[q] = a;
          }
        }
        _Float16* hb = layer ? &h1b[u][t & 1][0] : &h0b[u][t & 1][0];
        #pragma unroll
        for (int r = 0; r < 4; ++r){
          float gi = acc[0][r] + bias[0];
          float gf = acc[1][r] + bias[1];
          float gg = acc[2][r] + bias[2];
          float go = acc[3][r] + bias[3];
          float ii = sigf(gi), ff = sigf(gf), gt = tanh_fast(gg), oo = sigf(go);
          c[u][r] = ff*c[u][r] + ii*gt;
          float hn = oo * tanh_fast(c[u][r]);
          hb[(hi4*4 + r)*LP + wl*16 + lo] = (_Float16)hn;
        }
      }
    }
    __syncthreads();
    if (layer == 0){
      if (i < 11){
        #pragma unroll
        for (int u = 0; u < 2; ++u){
          const _Float16* rb = &h0b[u][i & 1][0];
          #pragma unroll
          for (int kt = 0; kt < 2; ++kt)
            ah[u][kt] = *(const half8*)&rb[lo*LP + kt*32 + hi4*8];
        }
      }
    } else {
      if (i < 12){
        #pragma unroll
        for (int u = 0; u < 2; ++u){
          const _Float16* rb = &h0b[u][i & 1][0];
          #pragma unroll
          for (int kt = 0; kt < 2; ++kt)
            ax[u][kt] = *(const half8*)&rb[lo*LP + kt*32 + hi4*8];
        }
      }
      if (i >= 1 && i < 12){
        #pragma unroll
        for (int u = 0; u < 2; ++u){
          const _Float16* rb = &h1b[u][(i-1) & 1][0];
          #pragma unroll
          for (int kt = 0; kt < 2; ++kt)
            ah[u][kt] = *(const half8*)&rb[lo*LP + kt*32 + hi4*8];
        }
      }
    }
  }
  // FC: h1(t=11) sits in h1b[u][1]; waves 4,5 handle tiles 0,1
  if (w == 4 || w == 5){
    int u = w - 4;
    const _Float16* rb = &h1b[u][1][0];
    half8 a0 = *(const half8*)&rb[lo*LP + 0*32 + hi4*8];
    half8 a1 = *(const half8*)&rb[lo*LP + 1*32 + hi4*8];
    floatx4 a = {0.f,0.f,0.f,0.f};
    a = __builtin_amdgcn_mfma_f32_16x16x32_f16(a0, FW[0], a, 0,0,0);
    a = __builtin_amdgcn_mfma_f32_16x16x32_f16(a1, FW[1], a, 0,0,0);
    float bo = fcb[lo];
    #pragma unroll
    for (int r = 0; r < 4; ++r){
      int n = nb0 + u*16 + hi4*4 + r;
      if (n < kNN) out[(size_t)n*kOUT + lo] = a[r] + bo;
    }
  }
}

extern "C" void kernel_launch(void* const* d_in, const int* in_sizes, int n_in,
                              void* d_out, int out_size, void* d_ws, size_t ws_size,
                              hipStream_t stream){
  const float* x    = (const float*)d_in[0];
  const int*   ei   = (const int*)  d_in[1];
  const float* gw0  = (const float*)d_in[2];
  const float* gb0  = (const float*)d_in[3];
  const float* gw1  = (const float*)d_in[4];
  const float* gb1  = (const float*)d_in[5];
  const float* wih0 = (const float*)d_in[6];
  const float* whh0 = (const float*)d_in[7];
  const float* bih0 = (const float*)d_in[8];
  const float* bhh0 = (const float*)d_in[9];
  const float* wih1 = (const float*)d_in[10];
  const float* whh1 = (const float*)d_in[11];
  const float* bih1 = (const float*)d_in[12];
  const float* bhh1 = (const float*)d_in[13];
  const float* fcw  = (const float*)d_in[14];
  const float* fcb  = (const float*)d_in[15];
  float* out = (float*)d_out;

  char* ws = (char*)d_ws;
  size_t p = 0;
  auto carve = [&](size_t bytes)->char*{
    char* r = ws + p;
    p += (bytes + 255) & ~(size_t)255;
    return r;
  };
  // anyf, cnt, cur contiguous -> single memset
  int*   anyf = (int*)  carve(256);
  int*   cnt  = (int*)  carve(sizeof(int)*kNN);
  int*   cur  = (int*)  carve(sizeof(int)*kNN);
  size_t zbytes = p;
  int*   offs = (int*)  carve(sizeof(int)*(kNN+1));
  float* dis  = (float*)carve(sizeof(float)*kNN);
  int2*  edat = (int2*) carve(sizeof(int2)*kNE);
  _Float16* xh   = (_Float16*)carve(sizeof(_Float16)*(size_t)kNN*kTT*kFIN); // 7.68MB
  _Float16* aggX = (_Float16*)carve(sizeof(_Float16)*(size_t)kNN*kTT*kFIN); // 7.68MB
  _Float16* bufA = (_Float16*)carve(sizeof(_Float16)*(size_t)kNN*kTT*kHH);  // 15.36MB
  _Float16* bufB = (_Float16*)carve(sizeof(_Float16)*(size_t)kNN*kTT*kHH);  // 15.36MB
  (void)ws_size; (void)in_sizes; (void)n_in; (void)out_size;

  hipMemsetAsync(ws, 0, zbytes, stream);
  k_detect_cast<<<120, 256, 0, stream>>>(ei, anyf, x, xh);
  k_deg    <<<(kNE+255)/256, 256, 0, stream>>>(ei, anyf, cnt);
  k_scan   <<<1, 256, 0, stream>>>(cnt, offs, dis);
  k_scatter<<<(kNE+255)/256, 256, 0, stream>>>(ei, anyf, offs, cur, dis, edat);

  // GCN-0: aggregate 32-feat x first (A_hat x), then GEMM (+gb0+relu), t-major
  k_agg<kFIN><<<(kNN*(kTT/4))/4, 256, 0, stream>>>(xh, aggX, dis, offs, edat);
  k_gemm<kFIN, kHH, false><<<(kNN*kTT)/64, 256, 0, stream>>>(aggX, gw0, gb0, bufB);
  // GCN-1: aggregate 64-feat, GEMM (+gb1+relu) writes node-major for LSTM
  k_agg<kHH><<<(kNN*(kTT/2))/4, 256, 0, stream>>>(bufB, bufA, dis, offs, edat);
  k_gemm<kHH, kHH, true><<<(kNN*kTT)/64, 256, 0, stream>>>(bufA, gw1, gb1, bufB);

  // Fused 2-layer LSTM + FC -> out (two 16-node tiles per block)
  k_rec2<<<(kNN+31)/32, 512, 0, stream>>>(bufB, wih0, whh0, bih0, bhh0,
                                          wih1, whh1, bih1, bhh1, fcw, fcb, out);
}